// Round 1
// 661.439 us; speedup vs baseline: 1.0272x; 1.0272x over previous
//
#include <hip/hip_runtime.h>

typedef __attribute__((ext_vector_type(8))) short bf16x8;
typedef __attribute__((ext_vector_type(4))) float f32x4;
typedef __attribute__((ext_vector_type(4))) unsigned short us4;

typedef __attribute__((address_space(3))) void lds_void_t;
typedef const __attribute__((address_space(1))) void gbl_void_t;

__device__ __forceinline__ float bf2f(unsigned short u) {
    union { unsigned int i; float f; } x; x.i = ((unsigned int)u) << 16; return x.f;
}
__device__ __forceinline__ unsigned short f2bf(float f) {
    union { float f; unsigned int i; } x; x.f = f;
    unsigned int u = x.i;
    unsigned int r = (u + 0x7FFFu + ((u >> 16) & 1u)) >> 16;  // RNE
    return (unsigned short)r;
}

// ---------------------------------------------------------------------------
// f32 -> bf16 convert, 4 elems/thread, grid-stride.
// ---------------------------------------------------------------------------
__global__ __launch_bounds__(256) void conv_f32_bf16(
    const float* __restrict__ src, unsigned short* __restrict__ dst, long n4)
{
    long i = (long)blockIdx.x * blockDim.x + threadIdx.x;
    const long stride = (long)gridDim.x * blockDim.x;
    const float4* s = (const float4*)src;
    for (; i < n4; i += stride) {
        float4 v = s[i];
        us4 o = { f2bf(v.x), f2bf(v.y), f2bf(v.z), f2bf(v.w) };
        *(us4*)&dst[i * 4] = o;
    }
}

// ---------------------------------------------------------------------------
// Transpose: W(K x N) f32 -> Wt(N x K) bf16. 64x64 LDS tiles.
// ---------------------------------------------------------------------------
__global__ __launch_bounds__(256) void transpose_f32_bf16(
    const float* __restrict__ W, unsigned short* __restrict__ Wt, int K, int N)
{
    __shared__ unsigned short t[64][65];
    const int n0 = blockIdx.x * 64, k0 = blockIdx.y * 64;
    const int tid = threadIdx.x;
#pragma unroll
    for (int i = 0; i < 16; i++) {
        const int idx = tid + i * 256;
        const int r = idx >> 6, c = idx & 63;
        t[c][r] = f2bf(W[(long)(k0 + r) * N + (n0 + c)]);
    }
    __syncthreads();
#pragma unroll
    for (int i = 0; i < 16; i++) {
        const int idx = tid + i * 256;
        const int r = idx >> 6, c = idx & 63;
        Wt[(long)(n0 + r) * K + (k0 + c)] = t[r][c];
    }
}

// ---------------------------------------------------------------------------
// 256x256 8-phase bf16 GEMM:  C[m][n] = sum_k A[m][k] * Bt[n][k]
// 8 waves (2M x 4N), per-wave 128x64 out, BK=64, LDS 128KiB (2 buf x 2 half).
// Schedule (T3+T4+T5, m201 template): per phase {ds_read subtile || 1 half-tile
// global_load_lds prefetch; s_barrier; lgkmcnt(0)+sched_barrier; setprio(1);
// 16 MFMA; setprio(0); barrier}. vmcnt(4) only at phases 4/8 (counted: 12
// outstanding, oldest 8 = next K-tile fully landed). Stage targets are
// region-safe: B-halves of a buf are fully read after ph2/ph6, A-halves after
// ph3/ph7; each stage is issued in a later, barrier-separated phase.
// T2 swizzle: 16B chunk c -> c ^ (row&7) within 128B rows, applied as
// inverse-swizzled GLOBAL source (gload_lds dest stays linear) + swizzled
// ds_read addr. Balanced: each ds_read_b128 touches every bank exactly 8x.
// SM: 0 = bf16 row-major (operand-SWAPPED mfma -> reg idx is 4 consecutive
//        cols -> us4 stores), 1 = VhT head-split-transpose (UNswapped, us4
//        along s), 2 = f32 row-major (swapped, float4 stores).
// SWZ: bijective chunked XCD swizzle (requires per-z-slice nwg % 8 == 0).
// ---------------------------------------------------------------------------
#define VMW(n) asm volatile("s_waitcnt vmcnt(" #n ")" ::: "memory")
#define BAR1() do { __builtin_amdgcn_sched_barrier(0); __builtin_amdgcn_s_barrier(); \
    asm volatile("s_waitcnt lgkmcnt(0)" ::: "memory"); __builtin_amdgcn_sched_barrier(0); \
    __builtin_amdgcn_s_setprio(1); } while (0)
#define BAR2() do { __builtin_amdgcn_s_setprio(0); __builtin_amdgcn_sched_barrier(0); \
    __builtin_amdgcn_s_barrier(); } while (0)

template <int SM, int SWZ>
__global__ __launch_bounds__(512, 2) void gemm256_bt(
    const unsigned short* __restrict__ A,
    const unsigned short* __restrict__ Bt,
    void* __restrict__ C,
    int K, int lda, int ldb, int ldc,
    long Ah, long Ab, long Bh, long Bb, long Ch, long Cb,
    int bg)
{
    const int tid  = threadIdx.x;
    const int wave = tid >> 6;
    const int lane = tid & 63;
    const int quad = lane >> 4;
    const int l16  = lane & 15;
    const int wm   = wave >> 2;   // 0..1 : M-wave (owns A-half wm)
    const int wn   = wave & 3;    // 0..3 : N-wave (owns B-half wn>>1, sub (wn&1))

    const int z = blockIdx.z;
    int lin = blockIdx.y * gridDim.x + blockIdx.x;
    if (SWZ) {
        const int q8 = (gridDim.x * gridDim.y) >> 3;  // nwg % 8 == 0 required
        lin = (lin & 7) * q8 + (lin >> 3);
    }
    const int by = lin / gridDim.x;
    const int m0 = by << 8;
    const int n0 = (lin - by * gridDim.x) << 8;

    const int h  = z / bg;
    const int bi = z - h * bg;
    A  += h * Ah + (long)bi * Ab;
    Bt += h * Bh + (long)bi * Bb;

    __shared__ __align__(16) unsigned short As[2][2][8192];  // [buf][half][128*64]
    __shared__ __align__(16) unsigned short Bs[2][2][8192];

    // ---- staging: linear LDS dest, inverse-swizzled global source ----
    const int srow = lane >> 3;                       // row within 8-row chunk
    const int scol = ((lane & 7) ^ srow) << 3;        // swizzled k-elem offset
    const long aoff0 = (long)(wave * 8 + srow) * lda + scol;        // chunk=wave
    const long aoff1 = (long)(64 + wave * 8 + srow) * lda + scol;   // chunk=8+wave
    const long boff0 = (long)(wave * 8 + srow) * ldb + scol;
    const long boff1 = (long)(64 + wave * 8 + srow) * ldb + scol;
    const unsigned short* Arow0 = A + (long)m0 * lda;
    const unsigned short* Arow1 = A + (long)(m0 + 128) * lda;
    const unsigned short* Brow0 = Bt + (long)n0 * ldb;
    const unsigned short* Brow1 = Bt + (long)(n0 + 128) * ldb;

#define STA(buf, hh, kt) do { \
    __builtin_amdgcn_global_load_lds((gbl_void_t*)(Arow##hh + aoff0 + (kt)), \
        (lds_void_t*)&As[buf][hh][wave << 9], 16, 0, 0); \
    __builtin_amdgcn_global_load_lds((gbl_void_t*)(Arow##hh + aoff1 + (kt)), \
        (lds_void_t*)&As[buf][hh][(8 + wave) << 9], 16, 0, 0); } while (0)
#define STB(buf, hh, kt) do { \
    __builtin_amdgcn_global_load_lds((gbl_void_t*)(Brow##hh + boff0 + (kt)), \
        (lds_void_t*)&Bs[buf][hh][wave << 9], 16, 0, 0); \
    __builtin_amdgcn_global_load_lds((gbl_void_t*)(Brow##hh + boff1 + (kt)), \
        (lds_void_t*)&Bs[buf][hh][(8 + wave) << 9], 16, 0, 0); } while (0)

    // ---- fragment reads (swizzled addr; row&7 == l16&7 for all frags) ----
    const int axorb = (l16 & 7) << 4;                       // byte XOR, bits 4-6
    const int k0 = ((quad << 4) ^ axorb) >> 1;              // kk=0, elems
    const int k1 = (((quad << 4) | 64) ^ axorb) >> 1;       // kk=1, elems
    const unsigned short* a0base = &As[0][wm][0];
    const unsigned short* a1base = &As[1][wm][0];
    const unsigned short* b0base = &Bs[0][wn >> 1][(wn & 1) << 12];
    const unsigned short* b1base = &Bs[1][wn >> 1][(wn & 1) << 12];

    bf16x8 ar[4][2];        // a-subtile: 4 m-frags x 2 kk
    bf16x8 br[2][2][2];     // [qn][ni2][kk] -- both qn sets kept live
    f32x4 acc[8][4];
#pragma unroll
    for (int i2 = 0; i2 < 8; i2++)
#pragma unroll
        for (int j2 = 0; j2 < 4; j2++) acc[i2][j2] = (f32x4){0.f, 0.f, 0.f, 0.f};

#define LDA_(qm, base) do { _Pragma("unroll") for (int u = 0; u < 4; u++) { \
    ar[u][0] = *(const bf16x8*)((base) + (((qm) * 64 + u * 16 + l16) << 6) + k0); \
    ar[u][1] = *(const bf16x8*)((base) + (((qm) * 64 + u * 16 + l16) << 6) + k1); } } while (0)
#define LDB_(qn, base) do { _Pragma("unroll") for (int v = 0; v < 2; v++) { \
    br[qn][v][0] = *(const bf16x8*)((base) + (((qn) * 32 + v * 16 + l16) << 6) + k0); \
    br[qn][v][1] = *(const bf16x8*)((base) + (((qn) * 32 + v * 16 + l16) << 6) + k1); } } while (0)
// SM==1 unswapped (old layout: col=l16); else swapped (row=l16, regs=4 cols)
#define MF(qm, qn) do { _Pragma("unroll") for (int kk = 0; kk < 2; kk++) \
    _Pragma("unroll") for (int u = 0; u < 4; u++) \
    _Pragma("unroll") for (int v = 0; v < 2; v++) { \
        if (SM == 1) acc[(qm) * 4 + u][(qn) * 2 + v] = __builtin_amdgcn_mfma_f32_16x16x32_bf16( \
            ar[u][kk], br[qn][v][kk], acc[(qm) * 4 + u][(qn) * 2 + v], 0, 0, 0); \
        else acc[(qm) * 4 + u][(qn) * 2 + v] = __builtin_amdgcn_mfma_f32_16x16x32_bf16( \
            br[qn][v][kk], ar[u][kk], acc[(qm) * 4 + u][(qn) * 2 + v], 0, 0, 0); \
    } } while (0)

    const int NITER = K >> 7;   // 2 K-tiles (BK=64) per iteration

    // prologue: tile0 (4 half-tiles) + tile1 B-halves; oldest 8 = tile0
    STA(0, 0, 0); STA(0, 1, 0);
    STB(0, 0, 0); STB(0, 1, 0);
    STB(1, 0, 64); STB(1, 1, 64);
    VMW(4);
    __builtin_amdgcn_s_barrier();

    for (int it = 0, t0 = 0; it < NITER; it++, t0 += 2) {
        const bool nl = (it + 1 < NITER);
        const int kA1 = (t0 + 1) << 6;
        const int kN2 = (t0 + 2) << 6;
        const int kN3 = (t0 + 3) << 6;
        // ---- phases 1-4: compute tile t0 from buf0 ----
        LDA_(0, a0base); LDB_(0, b0base);
        STA(1, 0, kA1);                       // buf1-A0 free since prev ph7
        BAR1(); MF(0, 0); BAR2();

        LDB_(1, b0base);
        STA(1, 1, kA1);
        BAR1(); MF(0, 1); BAR2();

        LDA_(1, a0base);
        if (nl) STB(0, 0, kN2);               // buf0-B fully read end-ph2
        BAR1(); MF(1, 1); BAR2();

        if (nl) { STB(0, 1, kN2); VMW(4); }   // oldest 8 = tile t0+1 landed
        else VMW(0);
        BAR1(); MF(1, 0); BAR2();
        // ---- phases 5-8: compute tile t0+1 from buf1 ----
        LDA_(0, a1base); LDB_(0, b1base);
        if (nl) STA(0, 0, kN2);               // buf0-A fully read end-ph3
        BAR1(); MF(0, 0); BAR2();

        LDB_(1, b1base);
        if (nl) STA(0, 1, kN2);
        BAR1(); MF(0, 1); BAR2();

        LDA_(1, a1base);
        if (nl) STB(1, 0, kN3);               // buf1-B fully read end-ph6
        BAR1(); MF(1, 1); BAR2();

        if (nl) { STB(1, 1, kN3); VMW(4); }   // oldest 8 = tile t0+2 landed
        BAR1(); MF(1, 0); BAR2();
    }

    // ---- epilogue (no DMA outstanding: drained at last iter's ph4) ----
    const long coff = h * Ch + (long)bi * Cb;
    if (SM == 0) {
        unsigned short* Cp = (unsigned short*)C + coff;
#pragma unroll
        for (int mi = 0; mi < 8; mi++) {
            const long rb = (long)(m0 + wm * 128 + mi * 16 + l16) * ldc;
#pragma unroll
            for (int ni = 0; ni < 4; ni++) {
                const int col = n0 + wn * 64 + ni * 16 + (quad << 2);
                us4 val = { f2bf(acc[mi][ni][0]), f2bf(acc[mi][ni][1]),
                            f2bf(acc[mi][ni][2]), f2bf(acc[mi][ni][3]) };
                *(us4*)&Cp[rb + col] = val;
            }
        }
    } else if (SM == 2) {
        float* Cp = (float*)C + coff;
#pragma unroll
        for (int mi = 0; mi < 8; mi++) {
            const long rb = (long)(m0 + wm * 128 + mi * 16 + l16) * ldc;
#pragma unroll
            for (int ni = 0; ni < 4; ni++) {
                const int col = n0 + wn * 64 + ni * 16 + (quad << 2);
                float4 v4 = { acc[mi][ni][0], acc[mi][ni][1],
                              acc[mi][ni][2], acc[mi][ni][3] };
                *(float4*)&Cp[rb + col] = v4;
            }
        }
    } else {  // SM == 1: VhT store, unswapped layout, us4 along s
        unsigned short* Cp = (unsigned short*)C;
#pragma unroll
        for (int mi = 0; mi < 8; mi++) {
#pragma unroll
            for (int ni = 0; ni < 4; ni++) {
                const int col = n0 + wn * 64 + ni * 16 + l16;
                const int h2 = col >> 9, d = col & 511;
                const int rowb = m0 + wm * 128 + mi * 16 + (quad << 2);
                const int bi2 = rowb >> 10, s = rowb & 1023;
                us4 val = { f2bf(acc[mi][ni][0]), f2bf(acc[mi][ni][1]),
                            f2bf(acc[mi][ni][2]), f2bf(acc[mi][ni][3]) };
                *(us4*)&Cp[(((long)(h2 * bg + bi2) * 512 + d) << 10) + s] = val;
            }
        }
    }
#undef STA
#undef STB
#undef LDA_
#undef LDB_
#undef MF
}
#undef VMW
#undef BAR1
#undef BAR2

// ---------------------------------------------------------------------------
// bf16 GEMM (128x128, legacy structure) -- kept for the fused scores (SM=3)
// and PV (SM=4) epilogues; see previous-round comments.
// ---------------------------------------------------------------------------
template <int SM, int SWZ>
__global__ __launch_bounds__(256) void gemm_bt(
    const unsigned short* __restrict__ A,
    const unsigned short* __restrict__ Bt,
    void* __restrict__ C,
    int K, int lda, int ldb, int ldc,
    long Ah, long Ab, long Bh, long Bb, long Ch, long Cb,
    int bg,
    const unsigned char* __restrict__ mask, float* __restrict__ L,
    float inv_temp, int b0)
{
    const int tid  = threadIdx.x;
    const int wave = tid >> 6;
    const int lane = tid & 63;
    const int quad = lane >> 4;
    const int l16  = lane & 15;

    int z, m0, n0;
    if (SWZ == 0) {
        z = blockIdx.z; m0 = blockIdx.y << 7; n0 = blockIdx.x << 7;
    } else {
        z = blockIdx.x * (gridDim.z >> 3) + (blockIdx.z >> 3);
        if (SWZ == 1) { n0 = (blockIdx.z & 7) << 7; m0 = blockIdx.y << 7; }
        else          { m0 = (blockIdx.z & 7) << 7; n0 = blockIdx.y << 7; }
    }
    const int h  = z / bg;
    const int bi = z - h * bg;
    A  += h * Ah + (long)bi * Ab;
    Bt += h * Bh + (long)bi * Bb;

    __shared__ __align__(16) unsigned short As[2][128 * 32];
    __shared__ __align__(16) unsigned short Bs[2][128 * 32];
    __shared__ float Ls[128];  // PV: summed softmax denominators

    if (SM == 4) {
        if (tid < 128) {
            const float* Lz = L + ((long)z << 10) + m0 + tid;
            const long sls = (long)gridDim.z << 10;
            float s = 0.f;
#pragma unroll
            for (int sl = 0; sl < 16; sl++) s += Lz[sl * sls];
            Ls[tid] = s;
        }
    }

    f32x4 acc[4][4];
#pragma unroll
    for (int i = 0; i < 4; i++)
#pragma unroll
        for (int j = 0; j < 4; j++) acc[i][j] = (f32x4){0.f, 0.f, 0.f, 0.f};

    const int wr = (wave >> 1) * 64;
    const int wc = (wave & 1) * 64;

    const int r0 = tid >> 2;
    const int kc = (tid & 3) ^ ((r0 >> 2) & 3);

    const unsigned short* A0 = A + (long)(m0 + r0) * lda + kc * 8;
    const unsigned short* A1 = A + (long)(m0 + r0 + 64) * lda + kc * 8;
    const unsigned short* B0 = Bt + (long)(n0 + r0) * ldb + kc * 8;
    const unsigned short* B1 = Bt + (long)(n0 + r0 + 64) * ldb + kc * 8;

    auto stage = [&](int buf, int kt) {
        __builtin_amdgcn_global_load_lds((gbl_void_t*)(A0 + kt),
            (lds_void_t*)&As[buf][(wave * 64) * 8], 16, 0, 0);
        __builtin_amdgcn_global_load_lds((gbl_void_t*)(A1 + kt),
            (lds_void_t*)&As[buf][(256 + wave * 64) * 8], 16, 0, 0);
        __builtin_amdgcn_global_load_lds((gbl_void_t*)(B0 + kt),
            (lds_void_t*)&Bs[buf][(wave * 64) * 8], 16, 0, 0);
        __builtin_amdgcn_global_load_lds((gbl_void_t*)(B1 + kt),
            (lds_void_t*)&Bs[buf][(256 + wave * 64) * 8], 16, 0, 0);
    };

    const int sw = (l16 >> 2) & 3;  // read-side XOR swizzle

    stage(0, 0);
    int cur = 0;
    for (int kt = 0; kt < K; kt += 32) {
        __syncthreads();  // drains DMA(cur) issued a full compute phase ago
        if (kt + 32 < K) stage(cur ^ 1, kt + 32);

        bf16x8 af[4], bf[4];
#pragma unroll
        for (int mi = 0; mi < 4; mi++)
            af[mi] = *(const bf16x8*)&As[cur][(wr + mi * 16 + l16) * 32 + ((quad ^ sw) << 3)];
#pragma unroll
        for (int ni = 0; ni < 4; ni++)
            bf[ni] = *(const bf16x8*)&Bs[cur][(wc + ni * 16 + l16) * 32 + ((quad ^ sw) << 3)];

#pragma unroll
        for (int mi = 0; mi < 4; mi++)
#pragma unroll
            for (int ni = 0; ni < 4; ni++)
                acc[mi][ni] = __builtin_amdgcn_mfma_f32_16x16x32_bf16(
                    af[mi], bf[ni], acc[mi][ni], 0, 0, 0);
        cur ^= 1;
    }

    const long coff = h * Ch + (long)bi * Cb;
    if (SM == 0) {
        unsigned short* Cp = (unsigned short*)C + coff;
#pragma unroll
        for (int mi = 0; mi < 4; mi++)
#pragma unroll
            for (int ni = 0; ni < 4; ni++) {
                const int col = n0 + wc + ni * 16 + l16;
#pragma unroll
                for (int r = 0; r < 4; r++) {
                    const int row = m0 + wr + mi * 16 + quad * 4 + r;
                    Cp[(long)row * ldc + col] = f2bf(acc[mi][ni][r]);
                }
            }
    } else if (SM == 1) {
        unsigned short* Cp = (unsigned short*)C;
#pragma unroll
        for (int mi = 0; mi < 4; mi++)
#pragma unroll
            for (int ni = 0; ni < 4; ni++) {
                const int col = n0 + wc + ni * 16 + l16;
                const int h2 = col >> 9, d = col & 511;
                const int rowb = m0 + wr + mi * 16 + quad * 4;
                const int bi2 = rowb >> 10, s = rowb & 1023;
                us4 val = { f2bf(acc[mi][ni][0]), f2bf(acc[mi][ni][1]),
                            f2bf(acc[mi][ni][2]), f2bf(acc[mi][ni][3]) };
                *(us4*)&Cp[(((long)(h2 * bg + bi2) * 512 + d) << 10) + s] = val;
            }
    } else if (SM == 2) {
        float* Cp = (float*)C + coff;
#pragma unroll
        for (int mi = 0; mi < 4; mi++)
#pragma unroll
            for (int ni = 0; ni < 4; ni++) {
                const int col = n0 + wc + ni * 16 + l16;
#pragma unroll
                for (int r = 0; r < 4; r++) {
                    const int row = m0 + wr + mi * 16 + quad * 4 + r;
                    Cp[(long)row * ldc + col] = acc[mi][ni][r];
                }
            }
    } else if (SM == 3) {
        unsigned short* Cp = (unsigned short*)C + coff;
        const unsigned char* mb = mask + ((long)(b0 + bi) << 20);
        const int slot = (n0 >> 7) * 2 + (wave & 1);
        float* Lz = L + ((long)(slot * gridDim.z + z) << 10);
#pragma unroll
        for (int mi = 0; mi < 4; mi++) {
#pragma unroll
            for (int r = 0; r < 4; r++) {
                const int row = m0 + wr + mi * 16 + quad * 4 + r;
                float rs = 0.f;
#pragma unroll
                for (int ni = 0; ni < 4; ni++) {
                    const int col = n0 + wc + ni * 16 + l16;
                    float p = __expf(acc[mi][ni][r] * inv_temp);
                    if (mb[((long)row << 10) + col] != 0) p = 0.f;
                    Cp[(long)row * ldc + col] = f2bf(p);
                    rs += p;
                }
#pragma unroll
                for (int m = 1; m < 16; m <<= 1) rs += __shfl_xor(rs, m);
                if (l16 == 0) Lz[row] = rs;
            }
        }
    } else {
        unsigned short* Cp = (unsigned short*)C + coff;
#pragma unroll
        for (int mi = 0; mi < 4; mi++)
#pragma unroll
            for (int r = 0; r < 4; r++) {
                const int row = m0 + wr + mi * 16 + quad * 4 + r;
                const float inv = 1.0f / Ls[row - m0];
#pragma unroll
                for (int ni = 0; ni < 4; ni++) {
                    const int col = n0 + wc + ni * 16 + l16;
                    Cp[(long)row * ldc + col] = f2bf(acc[mi][ni][r] * inv);
                }
            }
    }
}

// ---------------------------------------------------------------------------
// Fused: sum 4 split-K partials (f32, rows of 512) + LayerNorm -> f32 out.
// ---------------------------------------------------------------------------
__global__ __launch_bounds__(256) void ln_rows_red4(
    const float* __restrict__ Yp, long zs,
    const float* __restrict__ gamma,
    const float* __restrict__ beta,
    float* __restrict__ out)
{
    __shared__ float red[4];
    const long row = blockIdx.x;
    const float* y = Yp + (row << 9);
    const int tid = threadIdx.x;
    const int wave = tid >> 6, lane = tid & 63;

    float v0 = y[tid] + y[zs + tid] + y[2 * zs + tid] + y[3 * zs + tid];
    float v1 = y[tid + 256] + y[zs + tid + 256] + y[2 * zs + tid + 256] + y[3 * zs + tid + 256];
    float sm = v0 + v1;
#pragma unroll
    for (int i = 32; i > 0; i >>= 1) sm += __shfl_xor(sm, i);
    if (lane == 0) red[wave] = sm;
    __syncthreads();
    sm = red[0] + red[1] + red[2] + red[3];
    __syncthreads();
    const float mu = sm * (1.0f / 512.0f);

    const float d0 = v0 - mu, d1 = v1 - mu;
    float sq = d0 * d0 + d1 * d1;
#pragma unroll
    for (int i = 32; i > 0; i >>= 1) sq += __shfl_xor(sq, i);
    if (lane == 0) red[wave] = sq;
    __syncthreads();
    sq = red[0] + red[1] + red[2] + red[3];
    const float inv = rsqrtf(sq * (1.0f / 512.0f) + 1e-5f);

    out[(row << 9) + tid]       = d0 * inv * gamma[tid]       + beta[tid];
    out[(row << 9) + tid + 256] = d1 * inv * gamma[tid + 256] + beta[tid + 256];
}

// ---------------------------------------------------------------------------
extern "C" void kernel_launch(void* const* d_in, const int* in_sizes, int n_in,
                              void* d_out, int out_size, void* d_ws, size_t ws_size,
                              hipStream_t stream)
{
    const float* q_f  = (const float*)d_in[0];
    const float* k_f  = (const float*)d_in[1];
    const float* v_f  = (const float*)d_in[2];
    const float* Wq_f = (const float*)d_in[3];
    const float* Wk_f = (const float*)d_in[4];
    const float* Wv_f = (const float*)d_in[5];
    const float* Wo_f = (const float*)d_in[6];
    const float* ga_f = (const float*)d_in[7];
    const float* be_f = (const float*)d_in[8];
    const unsigned char* mask = (const unsigned char*)d_in[9];
    float* out = (float*)d_out;

    constexpr int B = 8, S = 1024, DM = 512, H = 8, DH = 512, HD = H * DH;  // HD=4096
    const float inv_temp = 0.044194173824159216f;  // 1/sqrt(512)

    size_t off = 0;
    auto alloc = [&](size_t bytes) {
        void* p = (char*)d_ws + off;
        off += (bytes + 255) & ~(size_t)255;
        return p;
    };
    unsigned short* qb  = (unsigned short*)alloc((size_t)B * S * DM * 2);
    unsigned short* kb  = (unsigned short*)alloc((size_t)B * S * DM * 2);
    unsigned short* vb  = (unsigned short*)alloc((size_t)B * S * DM * 2);
    unsigned short* WqT = (unsigned short*)alloc((size_t)HD * DM * 2);
    unsigned short* WkT = (unsigned short*)alloc((size_t)HD * DM * 2);
    unsigned short* WvT = (unsigned short*)alloc((size_t)HD * DM * 2);
    unsigned short* WoT = (unsigned short*)alloc((size_t)DH * HD * 2);
    const size_t fixed = off;

    // AO aliases Qh (dead after scores); Ypart aliases P (dead after PV).
    const size_t perbatch = (size_t)3 * S * HD * 2   // Qh(/AO), Kh, VhT
                          + (size_t)H * S * S * 2    // P / Ypart
                          + (size_t)16 * H * S * 4   // Lp (16 partial slots)
                          + 8 * 256;
    int bg = 8;
    while (bg > 1 && fixed + perbatch * (size_t)bg > ws_size) bg >>= 1;

    unsigned short* Qh  = (unsigned short*)alloc((size_t)bg * S * HD * 2);
    unsigned short* Kh  = (unsigned short*)alloc((size_t)bg * S * HD * 2);
    unsigned short* VhT = (unsigned short*)alloc((size_t)bg * S * HD * 2);
    unsigned short* AO  = Qh;  // alias: Qh dead once scores completes
    float* Lp = (float*)alloc((size_t)16 * H * bg * S * 4);
    void* PY = alloc((size_t)H * bg * S * S * 2);  // >= 4*bg*S*DH*4
    unsigned short* P = (unsigned short*)PY;
    float* Ypart = (float*)PY;

    // ---- canonicalization: f32 -> bf16 (+ weight transposes) ----
    const long nqkv4 = (long)B * S * DM / 4;
    conv_f32_bf16<<<2048, 256, 0, stream>>>(q_f, qb, nqkv4);
    conv_f32_bf16<<<2048, 256, 0, stream>>>(k_f, kb, nqkv4);
    conv_f32_bf16<<<2048, 256, 0, stream>>>(v_f, vb, nqkv4);
    transpose_f32_bf16<<<dim3(HD / 64, DM / 64), 256, 0, stream>>>(Wq_f, WqT, DM, HD);
    transpose_f32_bf16<<<dim3(HD / 64, DM / 64), 256, 0, stream>>>(Wk_f, WkT, DM, HD);
    transpose_f32_bf16<<<dim3(HD / 64, DM / 64), 256, 0, stream>>>(Wv_f, WvT, DM, HD);
    transpose_f32_bf16<<<dim3(DH / 64, HD / 64), 256, 0, stream>>>(Wo_f, WoT, HD, DH);

    for (int g = 0; g < B / bg; g++) {
        const long inoff = (long)g * bg * S * DM;
        const int  Mg = bg * S;
        const int  Z  = H * bg;

        // ---- QKV projections: (Mg x 512) x (512 x 4096), 256^2 8-phase ----
        gemm256_bt<0, 1><<<dim3(HD / 256, Mg / 256, 1), 512, 0, stream>>>(
            qb + inoff, WqT, Qh, DM, DM, DM, HD, 0, 0, 0, 0, 0, 0, bg);
        gemm256_bt<0, 1><<<dim3(HD / 256, Mg / 256, 1), 512, 0, stream>>>(
            kb + inoff, WkT, Kh, DM, DM, DM, HD, 0, 0, 0, 0, 0, 0, bg);
        gemm256_bt<1, 1><<<dim3(HD / 256, Mg / 256, 1), 512, 0, stream>>>(
            vb + inoff, WvT, VhT, DM, DM, DM, HD, 0, 0, 0, 0, 0, 0, bg);

        // ---- fused scores+exp+mask, XCD-swizzled (bx = z-subset, bz = n|zlow) ----
        gemm_bt<3, 1><<<dim3(8, 8, Z), 256, 0, stream>>>(
            Qh, Kh, P, DH, HD, HD, S,
            (long)DH, (long)S * HD,
            (long)DH, (long)S * HD,
            (long)bg * S * S, (long)S * S,
            bg, mask, Lp, inv_temp, g * bg);

        // ---- PV with 1/L normalization, XCD-swizzled (bz = m|zlow) ----
        gemm_bt<4, 2><<<dim3(8, 4, Z), 256, 0, stream>>>(
            P, VhT, AO, S, S, S, HD,
            (long)bg * S * S, (long)S * S,
            (long)bg * DH * S, (long)DH * S,
            (long)DH, (long)S * HD,
            bg, nullptr, Lp, 0.f, 0);

        // ---- O-projection, split-K x4 -> Ypart, 256^2 8-phase ----
        gemm256_bt<2, 1><<<dim3(DH / 256, Mg / 256, 4), 512, 0, stream>>>(
            AO, WoT, Ypart, HD / 4, HD, HD, DH,
            1024, 0, 1024, 0, (long)Mg * DH, 0, 1);

        // ---- reduce partials + LayerNorm -> f32 out ----
        ln_rows_red4<<<dim3(Mg), 256, 0, stream>>>(
            Ypart, (long)Mg * DH, ga_f, be_f, out + (long)g * bg * S * DH);
    }
}

// Round 2
// 635.767 us; speedup vs baseline: 1.0687x; 1.0404x over previous
//
#include <hip/hip_runtime.h>

typedef __attribute__((ext_vector_type(8))) short bf16x8;
typedef __attribute__((ext_vector_type(4))) float f32x4;
typedef __attribute__((ext_vector_type(4))) unsigned short us4;

typedef __attribute__((address_space(3))) void lds_void_t;
typedef const __attribute__((address_space(1))) void gbl_void_t;

__device__ __forceinline__ unsigned short f2bf(float f) {
    union { float f; unsigned int i; } x; x.f = f;
    unsigned int u = x.i;
    unsigned int r = (u + 0x7FFFu + ((u >> 16) & 1u)) >> 16;  // RNE
    return (unsigned short)r;
}

// ---------------------------------------------------------------------------
// f32 -> bf16 convert, 4 elems/thread, grid-stride.
// ---------------------------------------------------------------------------
__global__ __launch_bounds__(256) void conv_f32_bf16(
    const float* __restrict__ src, unsigned short* __restrict__ dst, long n4)
{
    long i = (long)blockIdx.x * blockDim.x + threadIdx.x;
    const long stride = (long)gridDim.x * blockDim.x;
    const float4* s = (const float4*)src;
    for (; i < n4; i += stride) {
        float4 v = s[i];
        us4 o = { f2bf(v.x), f2bf(v.y), f2bf(v.z), f2bf(v.w) };
        *(us4*)&dst[i * 4] = o;
    }
}

// ---------------------------------------------------------------------------
// Transpose: W(K x N) f32 -> Wt(N x K) bf16. 64x64 LDS tiles.
// ---------------------------------------------------------------------------
__global__ __launch_bounds__(256) void transpose_f32_bf16(
    const float* __restrict__ W, unsigned short* __restrict__ Wt, int K, int N)
{
    __shared__ unsigned short t[64][65];
    const int n0 = blockIdx.x * 64, k0 = blockIdx.y * 64;
    const int tid = threadIdx.x;
#pragma unroll
    for (int i = 0; i < 16; i++) {
        const int idx = tid + i * 256;
        const int r = idx >> 6, c = idx & 63;
        t[c][r] = f2bf(W[(long)(k0 + r) * N + (n0 + c)]);
    }
    __syncthreads();
#pragma unroll
    for (int i = 0; i < 16; i++) {
        const int idx = tid + i * 256;
        const int r = idx >> 6, c = idx & 63;
        Wt[(long)(n0 + r) * K + (k0 + c)] = t[r][c];
    }
}

// ---------------------------------------------------------------------------
// 256x256 8-phase bf16 GEMM:  C[m][n] = sum_k A[m][k] * Bt[n][k]
// 8 waves (2M x 4N), per-wave 128x64 out, BK=64, LDS 128KiB (2 buf x 2 half).
// Schedule (T3+T4+T5, m201 template, harness-verified round 1): per phase
// {ds_read subtile || 1 half-tile global_load_lds prefetch; s_barrier;
// lgkmcnt(0)+sched_barrier; setprio(1); 16 MFMA; setprio(0); barrier}.
// vmcnt(4) only at phases 4/8. Stage targets are region-safe (B-halves free
// after ph2/ph6, A-halves after ph3/ph7, barrier-separated).
// T2 swizzle: 16B chunk c -> c ^ (row&7) within 128B rows, applied as
// inverse-swizzled GLOBAL source (gload_lds dest stays linear) + swizzled
// ds_read addr.
// SM: 0 = bf16 row-major (operand-SWAPPED mfma -> reg idx = 4 consecutive
//        cols -> us4 stores)
//     1 = VhT head-split-transpose (UNswapped, us4 along s)
//     2 = f32 row-major (swapped, float4 stores)
//     3 = scores-fused: P=exp(s*it) w/ mask (uchar4), us4 stores; row-sums
//         reduced over ni/reg + shfl_xor(16,32) -> Lp[(nb*4+wn)][z][row]
//         (16 exclusive slots, quad==0 writes)
//     4 = PV: bf16 row-major scaled by 1/sum_{sl<16}(Lp[sl][z][row]), via
//         a 256-entry LDS table filled in the prologue
// SWZ: bijective chunked XCD swizzle (needs per-z nwg % 8 == 0). Only used
// where HBM locality matters (QKV / O-proj); scores/PV run at ~16% HBM.
// ---------------------------------------------------------------------------
#define VMW(n) asm volatile("s_waitcnt vmcnt(" #n ")" ::: "memory")
#define BAR1() do { __builtin_amdgcn_sched_barrier(0); __builtin_amdgcn_s_barrier(); \
    asm volatile("s_waitcnt lgkmcnt(0)" ::: "memory"); __builtin_amdgcn_sched_barrier(0); \
    __builtin_amdgcn_s_setprio(1); } while (0)
#define BAR2() do { __builtin_amdgcn_s_setprio(0); __builtin_amdgcn_sched_barrier(0); \
    __builtin_amdgcn_s_barrier(); } while (0)

template <int SM, int SWZ>
__global__ __launch_bounds__(512, 2) void gemm256_bt(
    const unsigned short* __restrict__ A,
    const unsigned short* __restrict__ Bt,
    void* __restrict__ C,
    int K, int lda, int ldb, int ldc,
    long Ah, long Ab, long Bh, long Bb, long Ch, long Cb,
    int bg,
    const unsigned char* __restrict__ mask, float* __restrict__ L,
    float inv_temp, int b0)
{
    const int tid  = threadIdx.x;
    const int wave = tid >> 6;
    const int lane = tid & 63;
    const int quad = lane >> 4;
    const int l16  = lane & 15;
    const int wm   = wave >> 2;   // 0..1 : M-wave (owns A-half wm)
    const int wn   = wave & 3;    // 0..3 : N-wave (owns B-half wn>>1, sub (wn&1))

    const int z = blockIdx.z;
    int lin = blockIdx.y * gridDim.x + blockIdx.x;
    if (SWZ) {
        const int q8 = (gridDim.x * gridDim.y) >> 3;  // nwg % 8 == 0 required
        lin = (lin & 7) * q8 + (lin >> 3);
    }
    const int by = lin / gridDim.x;
    const int m0 = by << 8;
    const int n0 = (lin - by * gridDim.x) << 8;

    const int h  = z / bg;
    const int bi = z - h * bg;
    A  += h * Ah + (long)bi * Ab;
    Bt += h * Bh + (long)bi * Bb;

    __shared__ __align__(16) unsigned short As[2][2][8192];  // [buf][half][128*64]
    __shared__ __align__(16) unsigned short Bs[2][2][8192];
    __shared__ float Ls[256];  // PV: summed softmax denominators

    if (SM == 4) {
        // sum the 16 partial slots once; loads fully consumed (ds_write dep)
        // before staging begins, so they don't perturb the counted vmcnt.
        if (tid < 256) {
            const float* Lz = L + ((long)z << 10) + m0 + tid;
            const long sls = (long)gridDim.z << 10;
            float s = 0.f;
#pragma unroll
            for (int sl = 0; sl < 16; sl++) s += Lz[sl * sls];
            Ls[tid] = s;
        }
    }

    // ---- staging: linear LDS dest, inverse-swizzled global source ----
    const int srow = lane >> 3;                       // row within 8-row chunk
    const int scol = ((lane & 7) ^ srow) << 3;        // swizzled k-elem offset
    const long aoff0 = (long)(wave * 8 + srow) * lda + scol;        // chunk=wave
    const long aoff1 = (long)(64 + wave * 8 + srow) * lda + scol;   // chunk=8+wave
    const long boff0 = (long)(wave * 8 + srow) * ldb + scol;
    const long boff1 = (long)(64 + wave * 8 + srow) * ldb + scol;
    const unsigned short* Arow0 = A + (long)m0 * lda;
    const unsigned short* Arow1 = A + (long)(m0 + 128) * lda;
    const unsigned short* Brow0 = Bt + (long)n0 * ldb;
    const unsigned short* Brow1 = Bt + (long)(n0 + 128) * ldb;

#define STA(buf, hh, kt) do { \
    __builtin_amdgcn_global_load_lds((gbl_void_t*)(Arow##hh + aoff0 + (kt)), \
        (lds_void_t*)&As[buf][hh][wave << 9], 16, 0, 0); \
    __builtin_amdgcn_global_load_lds((gbl_void_t*)(Arow##hh + aoff1 + (kt)), \
        (lds_void_t*)&As[buf][hh][(8 + wave) << 9], 16, 0, 0); } while (0)
#define STB(buf, hh, kt) do { \
    __builtin_amdgcn_global_load_lds((gbl_void_t*)(Brow##hh + boff0 + (kt)), \
        (lds_void_t*)&Bs[buf][hh][wave << 9], 16, 0, 0); \
    __builtin_amdgcn_global_load_lds((gbl_void_t*)(Brow##hh + boff1 + (kt)), \
        (lds_void_t*)&Bs[buf][hh][(8 + wave) << 9], 16, 0, 0); } while (0)

    // ---- fragment reads (swizzled addr; row&7 == l16&7 for all frags) ----
    const int axorb = (l16 & 7) << 4;                       // byte XOR, bits 4-6
    const int k0 = ((quad << 4) ^ axorb) >> 1;              // kk=0, elems
    const int k1 = (((quad << 4) | 64) ^ axorb) >> 1;       // kk=1, elems
    const unsigned short* a0base = &As[0][wm][0];
    const unsigned short* a1base = &As[1][wm][0];
    const unsigned short* b0base = &Bs[0][wn >> 1][(wn & 1) << 12];
    const unsigned short* b1base = &Bs[1][wn >> 1][(wn & 1) << 12];

    bf16x8 ar[4][2];        // a-subtile: 4 m-frags x 2 kk
    bf16x8 br[2][2][2];     // [qn][ni2][kk] -- both qn sets kept live
    f32x4 acc[8][4];
#pragma unroll
    for (int i2 = 0; i2 < 8; i2++)
#pragma unroll
        for (int j2 = 0; j2 < 4; j2++) acc[i2][j2] = (f32x4){0.f, 0.f, 0.f, 0.f};

#define LDA_(qm, base) do { _Pragma("unroll") for (int u = 0; u < 4; u++) { \
    ar[u][0] = *(const bf16x8*)((base) + (((qm) * 64 + u * 16 + l16) << 6) + k0); \
    ar[u][1] = *(const bf16x8*)((base) + (((qm) * 64 + u * 16 + l16) << 6) + k1); } } while (0)
#define LDB_(qn, base) do { _Pragma("unroll") for (int v = 0; v < 2; v++) { \
    br[qn][v][0] = *(const bf16x8*)((base) + (((qn) * 32 + v * 16 + l16) << 6) + k0); \
    br[qn][v][1] = *(const bf16x8*)((base) + (((qn) * 32 + v * 16 + l16) << 6) + k1); } } while (0)
// SM==1 unswapped (old layout: col=l16); else swapped (row=l16, regs=4 cols)
#define MF(qm, qn) do { _Pragma("unroll") for (int kk = 0; kk < 2; kk++) \
    _Pragma("unroll") for (int u = 0; u < 4; u++) \
    _Pragma("unroll") for (int v = 0; v < 2; v++) { \
        if (SM == 1) acc[(qm) * 4 + u][(qn) * 2 + v] = __builtin_amdgcn_mfma_f32_16x16x32_bf16( \
            ar[u][kk], br[qn][v][kk], acc[(qm) * 4 + u][(qn) * 2 + v], 0, 0, 0); \
        else acc[(qm) * 4 + u][(qn) * 2 + v] = __builtin_amdgcn_mfma_f32_16x16x32_bf16( \
            br[qn][v][kk], ar[u][kk], acc[(qm) * 4 + u][(qn) * 2 + v], 0, 0, 0); \
    } } while (0)

    const int NITER = K >> 7;   // 2 K-tiles (BK=64) per iteration

    // prologue: tile0 (4 half-tiles) + tile1 B-halves; oldest 8 = tile0
    STA(0, 0, 0); STA(0, 1, 0);
    STB(0, 0, 0); STB(0, 1, 0);
    STB(1, 0, 64); STB(1, 1, 64);
    VMW(4);
    __builtin_amdgcn_s_barrier();

    for (int it = 0, t0 = 0; it < NITER; it++, t0 += 2) {
        const bool nl = (it + 1 < NITER);
        const int kA1 = (t0 + 1) << 6;
        const int kN2 = (t0 + 2) << 6;
        const int kN3 = (t0 + 3) << 6;
        // ---- phases 1-4: compute tile t0 from buf0 ----
        LDA_(0, a0base); LDB_(0, b0base);
        STA(1, 0, kA1);                       // buf1-A0 free since prev ph7
        BAR1(); MF(0, 0); BAR2();

        LDB_(1, b0base);
        STA(1, 1, kA1);
        BAR1(); MF(0, 1); BAR2();

        LDA_(1, a0base);
        if (nl) STB(0, 0, kN2);               // buf0-B fully read end-ph2
        BAR1(); MF(1, 1); BAR2();

        if (nl) { STB(0, 1, kN2); VMW(4); }   // oldest 8 = tile t0+1 landed
        else VMW(0);
        BAR1(); MF(1, 0); BAR2();
        // ---- phases 5-8: compute tile t0+1 from buf1 ----
        LDA_(0, a1base); LDB_(0, b1base);
        if (nl) STA(0, 0, kN2);               // buf0-A fully read end-ph3
        BAR1(); MF(0, 0); BAR2();

        LDB_(1, b1base);
        if (nl) STA(0, 1, kN2);
        BAR1(); MF(0, 1); BAR2();

        LDA_(1, a1base);
        if (nl) STB(1, 0, kN3);               // buf1-B fully read end-ph6
        BAR1(); MF(1, 1); BAR2();

        if (nl) { STB(1, 1, kN3); VMW(4); }   // oldest 8 = tile t0+2 landed
        BAR1(); MF(1, 0); BAR2();
    }

    // ---- epilogue (no DMA outstanding: drained at last iter's ph4) ----
    const long coff = h * Ch + (long)bi * Cb;
    if (SM == 0) {
        unsigned short* Cp = (unsigned short*)C + coff;
#pragma unroll
        for (int mi = 0; mi < 8; mi++) {
            const long rb = (long)(m0 + wm * 128 + mi * 16 + l16) * ldc;
#pragma unroll
            for (int ni = 0; ni < 4; ni++) {
                const int col = n0 + wn * 64 + ni * 16 + (quad << 2);
                us4 val = { f2bf(acc[mi][ni][0]), f2bf(acc[mi][ni][1]),
                            f2bf(acc[mi][ni][2]), f2bf(acc[mi][ni][3]) };
                *(us4*)&Cp[rb + col] = val;
            }
        }
    } else if (SM == 2) {
        float* Cp = (float*)C + coff;
#pragma unroll
        for (int mi = 0; mi < 8; mi++) {
            const long rb = (long)(m0 + wm * 128 + mi * 16 + l16) * ldc;
#pragma unroll
            for (int ni = 0; ni < 4; ni++) {
                const int col = n0 + wn * 64 + ni * 16 + (quad << 2);
                float4 v4 = { acc[mi][ni][0], acc[mi][ni][1],
                              acc[mi][ni][2], acc[mi][ni][3] };
                *(float4*)&Cp[rb + col] = v4;
            }
        }
    } else if (SM == 1) {  // VhT store, unswapped layout, us4 along s
        unsigned short* Cp = (unsigned short*)C;
#pragma unroll
        for (int mi = 0; mi < 8; mi++) {
#pragma unroll
            for (int ni = 0; ni < 4; ni++) {
                const int col = n0 + wn * 64 + ni * 16 + l16;
                const int h2 = col >> 9, d = col & 511;
                const int rowb = m0 + wm * 128 + mi * 16 + (quad << 2);
                const int bi2 = rowb >> 10, s = rowb & 1023;
                us4 val = { f2bf(acc[mi][ni][0]), f2bf(acc[mi][ni][1]),
                            f2bf(acc[mi][ni][2]), f2bf(acc[mi][ni][3]) };
                *(us4*)&Cp[(((long)(h2 * bg + bi2) * 512 + d) << 10) + s] = val;
            }
        }
    } else if (SM == 3) {
        // fused scores epilogue (swapped layout: row=l16, regs=4 cols):
        // p = mask ? 0 : exp(s*inv_temp); us4 store; row-sum over ni/reg +
        // shfl_xor(16,32) across quads -> Lp[(nb*4+wn)][z][row], quad 0 writes.
        unsigned short* Cp = (unsigned short*)C + coff;
        const unsigned char* mb = mask + ((long)(b0 + bi) << 20);
        const int slot = (n0 >> 8) * 4 + wn;       // 4 n-blocks x 4 wn
        float* Lz = L + ((long)(slot * gridDim.z + z) << 10);
#pragma unroll
        for (int mi = 0; mi < 8; mi++) {
            const int row = m0 + wm * 128 + mi * 16 + l16;
            const long rb = (long)row * ldc;
            const long mrow = (long)row << 10;
            float rs = 0.f;
#pragma unroll
            for (int ni = 0; ni < 4; ni++) {
                const int col = n0 + wn * 64 + ni * 16 + (quad << 2);
                const uchar4 mv = *(const uchar4*)&mb[mrow + col];
                float p0 = __expf(acc[mi][ni][0] * inv_temp);
                float p1 = __expf(acc[mi][ni][1] * inv_temp);
                float p2 = __expf(acc[mi][ni][2] * inv_temp);
                float p3 = __expf(acc[mi][ni][3] * inv_temp);
                if (mv.x) p0 = 0.f;
                if (mv.y) p1 = 0.f;
                if (mv.z) p2 = 0.f;
                if (mv.w) p3 = 0.f;
                us4 val = { f2bf(p0), f2bf(p1), f2bf(p2), f2bf(p3) };
                *(us4*)&Cp[rb + col] = val;
                rs += p0 + p1 + p2 + p3;
            }
            rs += __shfl_xor(rs, 16);
            rs += __shfl_xor(rs, 32);
            if (quad == 0) Lz[row] = rs;
        }
    } else {
        // PV epilogue: scale by 1/Ls (LDS), us4 store along 4 consecutive cols.
        unsigned short* Cp = (unsigned short*)C + coff;
#pragma unroll
        for (int mi = 0; mi < 8; mi++) {
            const int ro = wm * 128 + mi * 16 + l16;
            const float inv = 1.0f / Ls[ro];
            const long rb = (long)(m0 + ro) * ldc;
#pragma unroll
            for (int ni = 0; ni < 4; ni++) {
                const int col = n0 + wn * 64 + ni * 16 + (quad << 2);
                us4 val = { f2bf(acc[mi][ni][0] * inv), f2bf(acc[mi][ni][1] * inv),
                            f2bf(acc[mi][ni][2] * inv), f2bf(acc[mi][ni][3] * inv) };
                *(us4*)&Cp[rb + col] = val;
            }
        }
    }
#undef STA
#undef STB
#undef LDA_
#undef LDB_
#undef MF
}
#undef VMW
#undef BAR1
#undef BAR2

// ---------------------------------------------------------------------------
// Fused: sum 4 split-K partials (f32, rows of 512) + LayerNorm -> f32 out.
// ---------------------------------------------------------------------------
__global__ __launch_bounds__(256) void ln_rows_red4(
    const float* __restrict__ Yp, long zs,
    const float* __restrict__ gamma,
    const float* __restrict__ beta,
    float* __restrict__ out)
{
    __shared__ float red[4];
    const long row = blockIdx.x;
    const float* y = Yp + (row << 9);
    const int tid = threadIdx.x;
    const int wave = tid >> 6, lane = tid & 63;

    float v0 = y[tid] + y[zs + tid] + y[2 * zs + tid] + y[3 * zs + tid];
    float v1 = y[tid + 256] + y[zs + tid + 256] + y[2 * zs + tid + 256] + y[3 * zs + tid + 256];
    float sm = v0 + v1;
#pragma unroll
    for (int i = 32; i > 0; i >>= 1) sm += __shfl_xor(sm, i);
    if (lane == 0) red[wave] = sm;
    __syncthreads();
    sm = red[0] + red[1] + red[2] + red[3];
    __syncthreads();
    const float mu = sm * (1.0f / 512.0f);

    const float d0 = v0 - mu, d1 = v1 - mu;
    float sq = d0 * d0 + d1 * d1;
#pragma unroll
    for (int i = 32; i > 0; i >>= 1) sq += __shfl_xor(sq, i);
    if (lane == 0) red[wave] = sq;
    __syncthreads();
    sq = red[0] + red[1] + red[2] + red[3];
    const float inv = rsqrtf(sq * (1.0f / 512.0f) + 1e-5f);

    out[(row << 9) + tid]       = d0 * inv * gamma[tid]       + beta[tid];
    out[(row << 9) + tid + 256] = d1 * inv * gamma[tid + 256] + beta[tid + 256];
}

// ---------------------------------------------------------------------------
extern "C" void kernel_launch(void* const* d_in, const int* in_sizes, int n_in,
                              void* d_out, int out_size, void* d_ws, size_t ws_size,
                              hipStream_t stream)
{
    const float* q_f  = (const float*)d_in[0];
    const float* k_f  = (const float*)d_in[1];
    const float* v_f  = (const float*)d_in[2];
    const float* Wq_f = (const float*)d_in[3];
    const float* Wk_f = (const float*)d_in[4];
    const float* Wv_f = (const float*)d_in[5];
    const float* Wo_f = (const float*)d_in[6];
    const float* ga_f = (const float*)d_in[7];
    const float* be_f = (const float*)d_in[8];
    const unsigned char* mask = (const unsigned char*)d_in[9];
    float* out = (float*)d_out;

    constexpr int B = 8, S = 1024, DM = 512, H = 8, DH = 512, HD = H * DH;  // HD=4096
    const float inv_temp = 0.044194173824159216f;  // 1/sqrt(512)

    size_t off = 0;
    auto alloc = [&](size_t bytes) {
        void* p = (char*)d_ws + off;
        off += (bytes + 255) & ~(size_t)255;
        return p;
    };
    unsigned short* qb  = (unsigned short*)alloc((size_t)B * S * DM * 2);
    unsigned short* kb  = (unsigned short*)alloc((size_t)B * S * DM * 2);
    unsigned short* vb  = (unsigned short*)alloc((size_t)B * S * DM * 2);
    unsigned short* WqT = (unsigned short*)alloc((size_t)HD * DM * 2);
    unsigned short* WkT = (unsigned short*)alloc((size_t)HD * DM * 2);
    unsigned short* WvT = (unsigned short*)alloc((size_t)HD * DM * 2);
    unsigned short* WoT = (unsigned short*)alloc((size_t)DH * HD * 2);
    const size_t fixed = off;

    // AO aliases Qh (dead after scores); Ypart aliases P (dead after PV).
    const size_t perbatch = (size_t)3 * S * HD * 2   // Qh(/AO), Kh, VhT
                          + (size_t)H * S * S * 2    // P / Ypart
                          + (size_t)16 * H * S * 4   // Lp (16 partial slots)
                          + 8 * 256;
    int bg = 8;
    while (bg > 1 && fixed + perbatch * (size_t)bg > ws_size) bg >>= 1;

    unsigned short* Qh  = (unsigned short*)alloc((size_t)bg * S * HD * 2);
    unsigned short* Kh  = (unsigned short*)alloc((size_t)bg * S * HD * 2);
    unsigned short* VhT = (unsigned short*)alloc((size_t)bg * S * HD * 2);
    unsigned short* AO  = Qh;  // alias: Qh dead once scores completes
    float* Lp = (float*)alloc((size_t)16 * H * bg * S * 4);
    void* PY = alloc((size_t)H * bg * S * S * 2);  // >= 4*bg*S*DH*4
    unsigned short* P = (unsigned short*)PY;
    float* Ypart = (float*)PY;

    // ---- canonicalization: f32 -> bf16 (+ weight transposes) ----
    const long nqkv4 = (long)B * S * DM / 4;
    conv_f32_bf16<<<2048, 256, 0, stream>>>(q_f, qb, nqkv4);
    conv_f32_bf16<<<2048, 256, 0, stream>>>(k_f, kb, nqkv4);
    conv_f32_bf16<<<2048, 256, 0, stream>>>(v_f, vb, nqkv4);
    transpose_f32_bf16<<<dim3(HD / 64, DM / 64), 256, 0, stream>>>(Wq_f, WqT, DM, HD);
    transpose_f32_bf16<<<dim3(HD / 64, DM / 64), 256, 0, stream>>>(Wk_f, WkT, DM, HD);
    transpose_f32_bf16<<<dim3(HD / 64, DM / 64), 256, 0, stream>>>(Wv_f, WvT, DM, HD);
    transpose_f32_bf16<<<dim3(DH / 64, HD / 64), 256, 0, stream>>>(Wo_f, WoT, HD, DH);

    for (int g = 0; g < B / bg; g++) {
        const long inoff = (long)g * bg * S * DM;
        const int  Mg = bg * S;
        const int  Z  = H * bg;

        // ---- QKV projections: (Mg x 512) x (512 x 4096), 256^2 8-phase ----
        gemm256_bt<0, 1><<<dim3(HD / 256, Mg / 256, 1), 512, 0, stream>>>(
            qb + inoff, WqT, Qh, DM, DM, DM, HD, 0, 0, 0, 0, 0, 0, bg,
            nullptr, nullptr, 0.f, 0);
        gemm256_bt<0, 1><<<dim3(HD / 256, Mg / 256, 1), 512, 0, stream>>>(
            kb + inoff, WkT, Kh, DM, DM, DM, HD, 0, 0, 0, 0, 0, 0, bg,
            nullptr, nullptr, 0.f, 0);
        gemm256_bt<1, 1><<<dim3(HD / 256, Mg / 256, 1), 512, 0, stream>>>(
            vb + inoff, WvT, VhT, DM, DM, DM, HD, 0, 0, 0, 0, 0, 0, bg,
            nullptr, nullptr, 0.f, 0);

        // ---- fused scores+exp+mask, 256^2 8-phase (K=512, NITER=4) ----
        gemm256_bt<3, 0><<<dim3(S / 256, S / 256, Z), 512, 0, stream>>>(
            Qh, Kh, P, DH, HD, HD, S,
            (long)DH, (long)S * HD,
            (long)DH, (long)S * HD,
            (long)bg * S * S, (long)S * S,
            bg, mask, Lp, inv_temp, g * bg);

        // ---- PV with 1/L normalization, 256^2 8-phase (K=1024, NITER=8) ----
        gemm256_bt<4, 0><<<dim3(DH / 256, S / 256, Z), 512, 0, stream>>>(
            P, VhT, AO, S, S, S, HD,
            (long)bg * S * S, (long)S * S,
            (long)bg * DH * S, (long)DH * S,
            (long)DH, (long)S * HD,
            bg, nullptr, Lp, 0.f, 0);

        // ---- O-projection, split-K x4 -> Ypart, 256^2 8-phase ----
        gemm256_bt<2, 1><<<dim3(DH / 256, Mg / 256, 4), 512, 0, stream>>>(
            AO, WoT, Ypart, HD / 4, HD, HD, DH,
            1024, 0, 1024, 0, (long)Mg * DH, 0, 1,
            nullptr, nullptr, 0.f, 0);

        // ---- reduce partials + LayerNorm -> f32 out ----
        ln_rows_red4<<<dim3(Mg), 256, 0, stream>>>(
            Ypart, (long)Mg * DH, ga_f, be_f, out + (long)g * bg * S * DH);
    }
}

// Round 3
// 604.910 us; speedup vs baseline: 1.1232x; 1.0510x over previous
//
#include <hip/hip_runtime.h>

typedef __attribute__((ext_vector_type(8))) short bf16x8;
typedef __attribute__((ext_vector_type(4))) float f32x4;
typedef __attribute__((ext_vector_type(4))) unsigned short us4;

typedef __attribute__((address_space(3))) void lds_void_t;
typedef const __attribute__((address_space(1))) void gbl_void_t;

__device__ __forceinline__ unsigned short f2bf(float f) {
    union { float f; unsigned int i; } x; x.f = f;
    unsigned int u = x.i;
    unsigned int r = (u + 0x7FFFu + ((u >> 16) & 1u)) >> 16;  // RNE
    return (unsigned short)r;
}

// ---------------------------------------------------------------------------
// f32 -> bf16 convert, 4 elems/thread, grid-stride.
// ---------------------------------------------------------------------------
__global__ __launch_bounds__(256) void conv_f32_bf16(
    const float* __restrict__ src, unsigned short* __restrict__ dst, long n4)
{
    long i = (long)blockIdx.x * blockDim.x + threadIdx.x;
    const long stride = (long)gridDim.x * blockDim.x;
    const float4* s = (const float4*)src;
    for (; i < n4; i += stride) {
        float4 v = s[i];
        us4 o = { f2bf(v.x), f2bf(v.y), f2bf(v.z), f2bf(v.w) };
        *(us4*)&dst[i * 4] = o;
    }
}

// ---------------------------------------------------------------------------
// Transpose: W(K x N) f32 -> Wt(N x K) bf16. 64x64 LDS tiles.
// ---------------------------------------------------------------------------
__global__ __launch_bounds__(256) void transpose_f32_bf16(
    const float* __restrict__ W, unsigned short* __restrict__ Wt, int K, int N)
{
    __shared__ unsigned short t[64][65];
    const int n0 = blockIdx.x * 64, k0 = blockIdx.y * 64;
    const int tid = threadIdx.x;
#pragma unroll
    for (int i = 0; i < 16; i++) {
        const int idx = tid + i * 256;
        const int r = idx >> 6, c = idx & 63;
        t[c][r] = f2bf(W[(long)(k0 + r) * N + (n0 + c)]);
    }
    __syncthreads();
#pragma unroll
    for (int i = 0; i < 16; i++) {
        const int idx = tid + i * 256;
        const int r = idx >> 6, c = idx & 63;
        Wt[(long)(n0 + r) * K + (k0 + c)] = t[r][c];
    }
}

// ---------------------------------------------------------------------------
// Mask summary: mf[b][row][nblk] = any(mask[b][row][nblk*256 .. +256)).
// One row per block; wave w ORs 256 bytes via ballot -> flag for nblk=w.
// ---------------------------------------------------------------------------
__global__ __launch_bounds__(256) void mask_any256(
    const unsigned char* __restrict__ mask, unsigned char* __restrict__ mf)
{
    const long row = blockIdx.x;                 // b*1024 + s
    const int tid = threadIdx.x;
    const unsigned int v = *(const unsigned int*)&mask[(row << 10) + (tid << 2)];
    const unsigned long long b = __ballot(v != 0u);
    if ((tid & 63) == 0) mf[(row << 2) + (tid >> 6)] = b ? 1 : 0;
}

// ---------------------------------------------------------------------------
// 256x256 bf16 GEMM, 16 waves (1024 thr, 4M x 4N, per-wave 64x64, acc=64 reg).
// BK=32, 4-buffer LDS (128 KiB), depth-3 prefetch, 2 phases per K-tile:
//   phA: {ds_read ar[4]+br[0..1] || STA(t+3)}; barrier; lgkm0; prio1; 8 MFMA
//   phB: {ds_read br[2..3]       || STB(t+3)+VMW(4)}; ...        ; 8 MFMA
// vmcnt ladder (oldest-first semantics): steady VMW(4) guarantees tile t+1
// landed with 4 loads in flight; tail VMW(2)/VMW(0) at t+3==NT / t+2==NT.
// Buffer (t+3)&3 == (t-1)&3: its reads completed at t-1 phB BAR2 (each wave
// passes lgkmcnt(0) before that barrier) -> overwrite at t phA is safe.
// T2 swizzle (BK=32, 64B rows, 4 chunks): read chunk = quad ^ ((l16>>1)&3)
// (2 lanes/bank = free, m136); staging source chunk = (lane&3)^((lane>>3)&3)
// (same involution; row = wave*16 + lane/4 makes g(row) wave-independent).
// gload_lds dest stays linear (rule #21).
// SM: 0 bf16 row-major (swapped mfma -> regs = 4 consecutive cols, us4)
//     1 VhT head-split-transpose (UNswapped, us4 along s)
//     2 f32 row-major (swapped, float4)
//     3 scores-fused: P=exp(s*it), mask via per-(row,nblk) flag (skip loads
//        when clear); us4 stores; row-sums -> Lp[(nb*4+wn)][z][row]
//     4 PV: scale by 1/sum_16(Lp), Ls[256] LDS table from prologue
// SWZ: 0 none | 1 within-plane XCD chunk (QKV/O-proj) | 2 whole-grid z-chunked
//      XCD swizzle (scores/PV: all blocks of ~4 consecutive z per XCD -> Q/K,
//      VhT panels stay L2-resident). Both bijective (total%8==0).
// ---------------------------------------------------------------------------
#define VMW(n) asm volatile("s_waitcnt vmcnt(" #n ")" ::: "memory")
#define BAR1() do { __builtin_amdgcn_sched_barrier(0); __builtin_amdgcn_s_barrier(); \
    asm volatile("s_waitcnt lgkmcnt(0)" ::: "memory"); __builtin_amdgcn_sched_barrier(0); \
    __builtin_amdgcn_s_setprio(1); } while (0)
#define BAR2() do { __builtin_amdgcn_s_setprio(0); __builtin_amdgcn_sched_barrier(0); \
    __builtin_amdgcn_s_barrier(); } while (0)

template <int SM, int SWZ>
__global__ __launch_bounds__(1024, 4) void gemm1k_bt(
    const unsigned short* __restrict__ A,
    const unsigned short* __restrict__ Bt,
    void* __restrict__ C,
    int K, int lda, int ldb, int ldc,
    long Ah, long Ab, long Bh, long Bb, long Ch, long Cb,
    int bg,
    const unsigned char* __restrict__ mask,
    const unsigned char* __restrict__ mflag,
    float* __restrict__ L,
    float inv_temp, int b0)
{
    const int tid  = threadIdx.x;
    const int wave = tid >> 6;
    const int lane = tid & 63;
    const int quad = lane >> 4;
    const int l16  = lane & 15;
    const int wm   = wave >> 2;   // 0..3 : M-wave (rows wm*64..+63)
    const int wn   = wave & 3;    // 0..3 : N-wave (cols wn*64..+63)

    int z, m0, n0;
    if (SWZ == 2) {
        const int gx = gridDim.x, gxy = gx * gridDim.y;
        const int tot = gxy * gridDim.z;
        int Lb = (blockIdx.z * gridDim.y + blockIdx.y) * gx + blockIdx.x;
        int t = (Lb & 7) * (tot >> 3) + (Lb >> 3);
        z = t / gxy;
        const int rem = t - z * gxy;
        const int by = rem / gx;
        m0 = by << 8; n0 = (rem - by * gx) << 8;
    } else if (SWZ == 1) {
        z = blockIdx.z;
        int lin = blockIdx.y * gridDim.x + blockIdx.x;
        const int q8 = (gridDim.x * gridDim.y) >> 3;
        lin = (lin & 7) * q8 + (lin >> 3);
        const int by = lin / gridDim.x;
        m0 = by << 8; n0 = (lin - by * gridDim.x) << 8;
    } else {
        z = blockIdx.z; m0 = blockIdx.y << 8; n0 = blockIdx.x << 8;
    }

    const int h  = z / bg;
    const int bi = z - h * bg;
    A  += h * Ah + (long)bi * Ab;
    Bt += h * Bh + (long)bi * Bb;

    __shared__ __align__(16) unsigned short As[4][8192];  // [buf][256*32]
    __shared__ __align__(16) unsigned short Bs[4][8192];
    __shared__ float Ls[256];  // PV: summed softmax denominators

    if (SM == 4) {
        // consumed (vmcnt-drained by compiler for the sum) before staging.
        if (tid < 256) {
            const float* Lz = L + ((long)z << 10) + m0 + tid;
            const long sls = (long)gridDim.z << 10;
            float s = 0.f;
#pragma unroll
            for (int sl = 0; sl < 16; sl++) s += Lz[sl * sls];
            Ls[tid] = s;
        }
    }

    // ---- staging: linear LDS dest, inverse-swizzled global source ----
    const int srow = lane >> 2;                               // row in wave's 16-row stripe
    const int scol = ((lane & 3) ^ ((lane >> 3) & 3)) << 3;   // swizzled k-elem offset
    const unsigned short* Ag = A + (long)(m0 + wave * 16 + srow) * lda + scol;
    const unsigned short* Bg = Bt + (long)(n0 + wave * 16 + srow) * ldb + scol;
    const int sdst = wave << 9;  // wave stripe: 16 rows x 32 elems

#define STA(buf, kt) __builtin_amdgcn_global_load_lds((gbl_void_t*)(Ag + (kt)), \
        (lds_void_t*)&As[buf][sdst], 16, 0, 0)
#define STB(buf, kt) __builtin_amdgcn_global_load_lds((gbl_void_t*)(Bg + (kt)), \
        (lds_void_t*)&Bs[buf][sdst], 16, 0, 0)

    // ---- fragment reads (swizzled addr) ----
    const int kof = (quad ^ ((l16 >> 1) & 3)) << 3;           // k-elem offset
    const int raA = ((wm * 64 + l16) << 5) + kof;
    const int raB = ((wn * 64 + l16) << 5) + kof;

    bf16x8 ar[4];
    bf16x8 br[4];
    f32x4 acc[4][4];
#pragma unroll
    for (int i2 = 0; i2 < 4; i2++)
#pragma unroll
        for (int j2 = 0; j2 < 4; j2++) acc[i2][j2] = (f32x4){0.f, 0.f, 0.f, 0.f};

#define LDA4(buf) do { _Pragma("unroll") for (int u = 0; u < 4; u++) \
    ar[u] = *(const bf16x8*)&As[buf][raA + u * 512]; } while (0)
#define LDB2(buf, hh) do { _Pragma("unroll") for (int v2 = 0; v2 < 2; v2++) \
    br[(hh) * 2 + v2] = *(const bf16x8*)&Bs[buf][raB + ((hh) * 2 + v2) * 512]; } while (0)
// SM==1 unswapped (store col=l16); else swapped (row=l16, regs = 4 cols)
#define MFH(hh) do { _Pragma("unroll") for (int u = 0; u < 4; u++) \
    _Pragma("unroll") for (int v2 = 0; v2 < 2; v2++) { \
        const int v = (hh) * 2 + v2; \
        if (SM == 1) acc[u][v] = __builtin_amdgcn_mfma_f32_16x16x32_bf16( \
            ar[u], br[v], acc[u][v], 0, 0, 0); \
        else acc[u][v] = __builtin_amdgcn_mfma_f32_16x16x32_bf16( \
            br[v], ar[u], acc[u][v], 0, 0, 0); \
    } } while (0)

    const int NT = K >> 5;   // K-tiles of 32

    // prologue: stage tiles 0,1,2; VMW(4) -> tile 0 landed
    STA(0, 0);  STB(0, 0);
    STA(1, 32); STB(1, 32);
    STA(2, 64); STB(2, 64);
    VMW(4);
    __builtin_amdgcn_s_barrier();

    for (int t = 0; t < NT; t++) {
        const int bcur = t & 3;
        const int bstg = (t + 3) & 3;
        const int kstg = (t + 3) << 5;
        const bool st = (t + 3 < NT);
        // phase A
        LDA4(bcur); LDB2(bcur, 0);
        if (st) STA(bstg, kstg);
        BAR1(); MFH(0); BAR2();
        // phase B
        LDB2(bcur, 1);
        if (st) { STB(bstg, kstg); VMW(4); }
        else if (t + 3 == NT) VMW(2);
        else if (t + 2 == NT) VMW(0);
        BAR1(); MFH(1); BAR2();
    }

    // ---- epilogue (all staging DMA drained by the tail ladder) ----
    const long coff = h * Ch + (long)bi * Cb;
    if (SM == 0) {
        unsigned short* Cp = (unsigned short*)C + coff;
#pragma unroll
        for (int mi = 0; mi < 4; mi++) {
            const long rb = (long)(m0 + wm * 64 + mi * 16 + l16) * ldc;
#pragma unroll
            for (int ni = 0; ni < 4; ni++) {
                const int col = n0 + wn * 64 + ni * 16 + (quad << 2);
                us4 val = { f2bf(acc[mi][ni][0]), f2bf(acc[mi][ni][1]),
                            f2bf(acc[mi][ni][2]), f2bf(acc[mi][ni][3]) };
                *(us4*)&Cp[rb + col] = val;
            }
        }
    } else if (SM == 2) {
        float* Cp = (float*)C + coff;
#pragma unroll
        for (int mi = 0; mi < 4; mi++) {
            const long rb = (long)(m0 + wm * 64 + mi * 16 + l16) * ldc;
#pragma unroll
            for (int ni = 0; ni < 4; ni++) {
                const int col = n0 + wn * 64 + ni * 16 + (quad << 2);
                float4 v4 = { acc[mi][ni][0], acc[mi][ni][1],
                              acc[mi][ni][2], acc[mi][ni][3] };
                *(float4*)&Cp[rb + col] = v4;
            }
        }
    } else if (SM == 1) {  // VhT store, unswapped layout, us4 along s
        unsigned short* Cp = (unsigned short*)C;
#pragma unroll
        for (int mi = 0; mi < 4; mi++) {
#pragma unroll
            for (int ni = 0; ni < 4; ni++) {
                const int col = n0 + wn * 64 + ni * 16 + l16;
                const int h2 = col >> 9, d = col & 511;
                const int rowb = m0 + wm * 64 + mi * 16 + (quad << 2);
                const int bi2 = rowb >> 10, s = rowb & 1023;
                us4 val = { f2bf(acc[mi][ni][0]), f2bf(acc[mi][ni][1]),
                            f2bf(acc[mi][ni][2]), f2bf(acc[mi][ni][3]) };
                *(us4*)&Cp[(((long)(h2 * bg + bi2) * 512 + d) << 10) + s] = val;
            }
        }
    } else if (SM == 3) {
        // scores epilogue (swapped: row=l16, regs = 4 cols). Mask applied only
        // when the per-(row, 256-col-block) flag says the block has any bits.
        unsigned short* Cp = (unsigned short*)C + coff;
        const unsigned char* mb = mask + ((long)(b0 + bi) << 20);
        const unsigned char* mfb = mflag + ((long)(b0 + bi) << 12);
        const int slot = (n0 >> 8) * 4 + wn;       // 4 n-blocks x 4 wn
        float* Lz = L + ((long)(slot * gridDim.z + z) << 10);
#pragma unroll
        for (int mi = 0; mi < 4; mi++) {
            const int row = m0 + wm * 64 + mi * 16 + l16;
            const long rb = (long)row * ldc;
            const unsigned char fl = mfb[(row << 2) + (n0 >> 8)];
            float rs = 0.f;
#pragma unroll
            for (int ni = 0; ni < 4; ni++) {
                const int col = n0 + wn * 64 + ni * 16 + (quad << 2);
                float p0 = __expf(acc[mi][ni][0] * inv_temp);
                float p1 = __expf(acc[mi][ni][1] * inv_temp);
                float p2 = __expf(acc[mi][ni][2] * inv_temp);
                float p3 = __expf(acc[mi][ni][3] * inv_temp);
                if (fl) {
                    const uchar4 mv = *(const uchar4*)&mb[((long)row << 10) + col];
                    if (mv.x) p0 = 0.f;
                    if (mv.y) p1 = 0.f;
                    if (mv.z) p2 = 0.f;
                    if (mv.w) p3 = 0.f;
                }
                us4 val = { f2bf(p0), f2bf(p1), f2bf(p2), f2bf(p3) };
                *(us4*)&Cp[rb + col] = val;
                rs += p0 + p1 + p2 + p3;
            }
            rs += __shfl_xor(rs, 16);
            rs += __shfl_xor(rs, 32);
            if (quad == 0) Lz[row] = rs;
        }
    } else {
        // PV epilogue: scale by 1/Ls (LDS), us4 along 4 consecutive cols.
        unsigned short* Cp = (unsigned short*)C + coff;
#pragma unroll
        for (int mi = 0; mi < 4; mi++) {
            const int ro = wm * 64 + mi * 16 + l16;
            const float inv = 1.0f / Ls[ro];
            const long rb = (long)(m0 + ro) * ldc;
#pragma unroll
            for (int ni = 0; ni < 4; ni++) {
                const int col = n0 + wn * 64 + ni * 16 + (quad << 2);
                us4 val = { f2bf(acc[mi][ni][0] * inv), f2bf(acc[mi][ni][1] * inv),
                            f2bf(acc[mi][ni][2] * inv), f2bf(acc[mi][ni][3] * inv) };
                *(us4*)&Cp[rb + col] = val;
            }
        }
    }
#undef STA
#undef STB
#undef LDA4
#undef LDB2
#undef MFH
}
#undef VMW
#undef BAR1
#undef BAR2

// ---------------------------------------------------------------------------
// Fused: sum 4 split-K partials (f32, rows of 512) + LayerNorm -> f32 out.
// ---------------------------------------------------------------------------
__global__ __launch_bounds__(256) void ln_rows_red4(
    const float* __restrict__ Yp, long zs,
    const float* __restrict__ gamma,
    const float* __restrict__ beta,
    float* __restrict__ out)
{
    __shared__ float red[4];
    const long row = blockIdx.x;
    const float* y = Yp + (row << 9);
    const int tid = threadIdx.x;
    const int wave = tid >> 6, lane = tid & 63;

    float v0 = y[tid] + y[zs + tid] + y[2 * zs + tid] + y[3 * zs + tid];
    float v1 = y[tid + 256] + y[zs + tid + 256] + y[2 * zs + tid + 256] + y[3 * zs + tid + 256];
    float sm = v0 + v1;
#pragma unroll
    for (int i = 32; i > 0; i >>= 1) sm += __shfl_xor(sm, i);
    if (lane == 0) red[wave] = sm;
    __syncthreads();
    sm = red[0] + red[1] + red[2] + red[3];
    __syncthreads();
    const float mu = sm * (1.0f / 512.0f);

    const float d0 = v0 - mu, d1 = v1 - mu;
    float sq = d0 * d0 + d1 * d1;
#pragma unroll
    for (int i = 32; i > 0; i >>= 1) sq += __shfl_xor(sq, i);
    if (lane == 0) red[wave] = sq;
    __syncthreads();
    sq = red[0] + red[1] + red[2] + red[3];
    const float inv = rsqrtf(sq * (1.0f / 512.0f) + 1e-5f);

    out[(row << 9) + tid]       = d0 * inv * gamma[tid]       + beta[tid];
    out[(row << 9) + tid + 256] = d1 * inv * gamma[tid + 256] + beta[tid + 256];
}

// ---------------------------------------------------------------------------
extern "C" void kernel_launch(void* const* d_in, const int* in_sizes, int n_in,
                              void* d_out, int out_size, void* d_ws, size_t ws_size,
                              hipStream_t stream)
{
    const float* q_f  = (const float*)d_in[0];
    const float* k_f  = (const float*)d_in[1];
    const float* v_f  = (const float*)d_in[2];
    const float* Wq_f = (const float*)d_in[3];
    const float* Wk_f = (const float*)d_in[4];
    const float* Wv_f = (const float*)d_in[5];
    const float* Wo_f = (const float*)d_in[6];
    const float* ga_f = (const float*)d_in[7];
    const float* be_f = (const float*)d_in[8];
    const unsigned char* mask = (const unsigned char*)d_in[9];
    float* out = (float*)d_out;

    constexpr int B = 8, S = 1024, DM = 512, H = 8, DH = 512, HD = H * DH;  // HD=4096
    const float inv_temp = 0.044194173824159216f;  // 1/sqrt(512)

    size_t off = 0;
    auto alloc = [&](size_t bytes) {
        void* p = (char*)d_ws + off;
        off += (bytes + 255) & ~(size_t)255;
        return p;
    };
    unsigned short* qb  = (unsigned short*)alloc((size_t)B * S * DM * 2);
    unsigned short* kb  = (unsigned short*)alloc((size_t)B * S * DM * 2);
    unsigned short* vb  = (unsigned short*)alloc((size_t)B * S * DM * 2);
    unsigned short* WqT = (unsigned short*)alloc((size_t)HD * DM * 2);
    unsigned short* WkT = (unsigned short*)alloc((size_t)HD * DM * 2);
    unsigned short* WvT = (unsigned short*)alloc((size_t)HD * DM * 2);
    unsigned short* WoT = (unsigned short*)alloc((size_t)DH * HD * 2);
    unsigned char* mf   = (unsigned char*)alloc((size_t)B * S * 4);  // mask flags
    const size_t fixed = off;

    // AO aliases Qh (dead after scores); Ypart aliases P (dead after PV).
    const size_t perbatch = (size_t)3 * S * HD * 2   // Qh(/AO), Kh, VhT
                          + (size_t)H * S * S * 2    // P / Ypart
                          + (size_t)16 * H * S * 4   // Lp (16 partial slots)
                          + 8 * 256;
    int bg = 8;
    while (bg > 1 && fixed + perbatch * (size_t)bg > ws_size) bg >>= 1;

    unsigned short* Qh  = (unsigned short*)alloc((size_t)bg * S * HD * 2);
    unsigned short* Kh  = (unsigned short*)alloc((size_t)bg * S * HD * 2);
    unsigned short* VhT = (unsigned short*)alloc((size_t)bg * S * HD * 2);
    unsigned short* AO  = Qh;  // alias: Qh dead once scores completes
    float* Lp = (float*)alloc((size_t)16 * H * bg * S * 4);
    void* PY = alloc((size_t)H * bg * S * S * 2);  // >= 4*bg*S*DH*4
    unsigned short* P = (unsigned short*)PY;
    float* Ypart = (float*)PY;

    // ---- canonicalization: f32 -> bf16 (+ weight transposes, mask flags) ----
    const long nqkv4 = (long)B * S * DM / 4;
    conv_f32_bf16<<<2048, 256, 0, stream>>>(q_f, qb, nqkv4);
    conv_f32_bf16<<<2048, 256, 0, stream>>>(k_f, kb, nqkv4);
    conv_f32_bf16<<<2048, 256, 0, stream>>>(v_f, vb, nqkv4);
    transpose_f32_bf16<<<dim3(HD / 64, DM / 64), 256, 0, stream>>>(Wq_f, WqT, DM, HD);
    transpose_f32_bf16<<<dim3(HD / 64, DM / 64), 256, 0, stream>>>(Wk_f, WkT, DM, HD);
    transpose_f32_bf16<<<dim3(HD / 64, DM / 64), 256, 0, stream>>>(Wv_f, WvT, DM, HD);
    transpose_f32_bf16<<<dim3(DH / 64, HD / 64), 256, 0, stream>>>(Wo_f, WoT, HD, DH);
    mask_any256<<<dim3(B * S), 256, 0, stream>>>(mask, mf);

    for (int g = 0; g < B / bg; g++) {
        const long inoff = (long)g * bg * S * DM;
        const int  Mg = bg * S;
        const int  Z  = H * bg;

        // ---- QKV projections: (Mg x 512) x (512 x 4096) ----
        gemm1k_bt<0, 1><<<dim3(HD / 256, Mg / 256, 1), 1024, 0, stream>>>(
            qb + inoff, WqT, Qh, DM, DM, DM, HD, 0, 0, 0, 0, 0, 0, bg,
            nullptr, nullptr, nullptr, 0.f, 0);
        gemm1k_bt<0, 1><<<dim3(HD / 256, Mg / 256, 1), 1024, 0, stream>>>(
            kb + inoff, WkT, Kh, DM, DM, DM, HD, 0, 0, 0, 0, 0, 0, bg,
            nullptr, nullptr, nullptr, 0.f, 0);
        gemm1k_bt<1, 1><<<dim3(HD / 256, Mg / 256, 1), 1024, 0, stream>>>(
            vb + inoff, WvT, VhT, DM, DM, DM, HD, 0, 0, 0, 0, 0, 0, bg,
            nullptr, nullptr, nullptr, 0.f, 0);

        // ---- fused scores+exp+mask, z-chunked XCD swizzle ----
        gemm1k_bt<3, 2><<<dim3(S / 256, S / 256, Z), 1024, 0, stream>>>(
            Qh, Kh, P, DH, HD, HD, S,
            (long)DH, (long)S * HD,
            (long)DH, (long)S * HD,
            (long)bg * S * S, (long)S * S,
            bg, mask, mf, Lp, inv_temp, g * bg);

        // ---- PV with 1/L normalization, z-chunked XCD swizzle ----
        gemm1k_bt<4, 2><<<dim3(DH / 256, S / 256, Z), 1024, 0, stream>>>(
            P, VhT, AO, S, S, S, HD,
            (long)bg * S * S, (long)S * S,
            (long)bg * DH * S, (long)DH * S,
            (long)DH, (long)S * HD,
            bg, nullptr, nullptr, Lp, 0.f, 0);

        // ---- O-projection, split-K x4 -> Ypart ----
        gemm1k_bt<2, 1><<<dim3(DH / 256, Mg / 256, 4), 1024, 0, stream>>>(
            AO, WoT, Ypart, HD / 4, HD, HD, DH,
            1024, 0, 1024, 0, (long)Mg * DH, 0, 1,
            nullptr, nullptr, nullptr, 0.f, 0);

        // ---- reduce partials + LayerNorm -> f32 out ----
        ln_rows_red4<<<dim3(Mg), 256, 0, stream>>>(
            Ypart, (long)Mg * DH, ga_f, be_f, out + (long)g * bg * S * DH);
    }
}

// Round 4
// 581.522 us; speedup vs baseline: 1.1683x; 1.0402x over previous
//
#include <hip/hip_runtime.h>

typedef __attribute__((ext_vector_type(8))) short bf16x8;
typedef __attribute__((ext_vector_type(4))) float f32x4;
typedef __attribute__((ext_vector_type(4))) unsigned short us4;

typedef __attribute__((address_space(3))) void lds_void_t;
typedef const __attribute__((address_space(1))) void gbl_void_t;

__device__ __forceinline__ unsigned short f2bf(float f) {
    union { float f; unsigned int i; } x; x.f = f;
    unsigned int u = x.i;
    unsigned int r = (u + 0x7FFFu + ((u >> 16) & 1u)) >> 16;  // RNE
    return (unsigned short)r;
}

// ---------------------------------------------------------------------------
// f32 -> bf16 convert, 4 elems/thread, grid-stride.
// ---------------------------------------------------------------------------
__global__ __launch_bounds__(256) void conv_f32_bf16(
    const float* __restrict__ src, unsigned short* __restrict__ dst, long n4)
{
    long i = (long)blockIdx.x * blockDim.x + threadIdx.x;
    const long stride = (long)gridDim.x * blockDim.x;
    const float4* s = (const float4*)src;
    for (; i < n4; i += stride) {
        float4 v = s[i];
        us4 o = { f2bf(v.x), f2bf(v.y), f2bf(v.z), f2bf(v.w) };
        *(us4*)&dst[i * 4] = o;
    }
}

// ---------------------------------------------------------------------------
// Transpose: W(K x N) f32 -> Wt(N x K) bf16. 64x64 LDS tiles.
// ---------------------------------------------------------------------------
__global__ __launch_bounds__(256) void transpose_f32_bf16(
    const float* __restrict__ W, unsigned short* __restrict__ Wt, int K, int N)
{
    __shared__ unsigned short t[64][65];
    const int n0 = blockIdx.x * 64, k0 = blockIdx.y * 64;
    const int tid = threadIdx.x;
#pragma unroll
    for (int i = 0; i < 16; i++) {
        const int idx = tid + i * 256;
        const int r = idx >> 6, c = idx & 63;
        t[c][r] = f2bf(W[(long)(k0 + r) * N + (n0 + c)]);
    }
    __syncthreads();
#pragma unroll
    for (int i = 0; i < 16; i++) {
        const int idx = tid + i * 256;
        const int r = idx >> 6, c = idx & 63;
        Wt[(long)(n0 + r) * K + (k0 + c)] = t[r][c];
    }
}

// ---------------------------------------------------------------------------
// Mask summary: mf[b][row][nblk] = any(mask[b][row][nblk*256 .. +256)).
// ---------------------------------------------------------------------------
__global__ __launch_bounds__(256) void mask_any256(
    const unsigned char* __restrict__ mask, unsigned char* __restrict__ mf)
{
    const long row = blockIdx.x;                 // b*1024 + s
    const int tid = threadIdx.x;
    const unsigned int v = *(const unsigned int*)&mask[(row << 10) + (tid << 2)];
    const unsigned long long b = __ballot(v != 0u);
    if ((tid & 63) == 0) mf[(row << 2) + (tid >> 6)] = b ? 1 : 0;
}

// ---------------------------------------------------------------------------
// 256x256 bf16 GEMM, 8 waves (512 thr), wave tile 128x64 (wm=wave>>2 rows,
// wn=wave&3 cols), acc 8x4 f32x4 (128 VGPR), BK=32, 4 LDS buffers (128 KiB),
// depth-3 prefetch, ONE barrier-pair per K-tile:
//   per tile t: {ds_read 12 (ar[8]+br[4] from buf t&3) || stage tile t+3
//   (4 gloads) ; VMW}; BAR1(=sbar+lgkm0+prio1); 32 MFMA; BAR2.
// vmcnt ladder (oldest-first): steady VMW(8) with 12 in flight -> tile t+1's
// 4 loads landed; tail VMW(4) @ t==NT-3, VMW(0) @ t==NT-2.
// Safety chain (verified r3): wave X arrives at BAR2(t-1) only after its
// lgkmcnt(0) in BAR1(t-1) drained its reads of buf (t+3)&3 == (t-1)&3, and
// staging at t is issued after BAR2(t-1) release -> no WAR race. Cross-wave
// DMA visibility: every wave's VMW for tile T precedes a barrier that
// precedes any wave's reads of tile T.
// T2 swizzle pair (verified r3, 0 bank conflicts): stage source col chunk =
// (lane&3)^((lane>>3)&3), LDS dest linear; read chunk = quad^((l16>>1)&3).
// SM: 0 bf16 row-major (swapped mfma -> regs = 4 consecutive cols, us4)
//     1 VhT head-split-transpose (UNswapped, us4 along s)
//     2 f32 row-major (swapped, float4)
//     3 scores-fused: P=exp(s*it), mask via per-(row,nblk) flag; us4 stores;
//        row-sums -> Lp[(nb*4+wn)][z][row] (16 exclusive slots)
//     4 PV: scale by 1/sum_16(Lp), Ls[256] LDS table from prologue
// SWZ: 0 none | 1 within-plane XCD chunk | 2 whole-grid z-chunked XCD swizzle
// ---------------------------------------------------------------------------
#define VMW(n) asm volatile("s_waitcnt vmcnt(" #n ")" ::: "memory")
#define BAR1() do { __builtin_amdgcn_sched_barrier(0); __builtin_amdgcn_s_barrier(); \
    asm volatile("s_waitcnt lgkmcnt(0)" ::: "memory"); __builtin_amdgcn_sched_barrier(0); \
    __builtin_amdgcn_s_setprio(1); } while (0)
#define BAR2() do { __builtin_amdgcn_s_setprio(0); __builtin_amdgcn_sched_barrier(0); \
    __builtin_amdgcn_s_barrier(); } while (0)

template <int SM, int SWZ>
__global__ __launch_bounds__(512, 2) void gemm8w_bt(
    const unsigned short* __restrict__ A,
    const unsigned short* __restrict__ Bt,
    void* __restrict__ C,
    int K, int lda, int ldb, int ldc,
    long Ah, long Ab, long Bh, long Bb, long Ch, long Cb,
    int bg,
    const unsigned char* __restrict__ mask,
    const unsigned char* __restrict__ mflag,
    float* __restrict__ L,
    float inv_temp, int b0)
{
    const int tid  = threadIdx.x;
    const int wave = tid >> 6;
    const int lane = tid & 63;
    const int quad = lane >> 4;
    const int l16  = lane & 15;
    const int wm   = wave >> 2;   // 0..1 : M-wave (rows wm*128..+127)
    const int wn   = wave & 3;    // 0..3 : N-wave (cols wn*64..+63)

    int z, m0, n0;
    if (SWZ == 2) {
        const int gx = gridDim.x, gxy = gx * gridDim.y;
        const int tot = gxy * gridDim.z;
        int Lb = (blockIdx.z * gridDim.y + blockIdx.y) * gx + blockIdx.x;
        int t = (Lb & 7) * (tot >> 3) + (Lb >> 3);
        z = t / gxy;
        const int rem = t - z * gxy;
        const int by = rem / gx;
        m0 = by << 8; n0 = (rem - by * gx) << 8;
    } else if (SWZ == 1) {
        z = blockIdx.z;
        int lin = blockIdx.y * gridDim.x + blockIdx.x;
        const int q8 = (gridDim.x * gridDim.y) >> 3;
        lin = (lin & 7) * q8 + (lin >> 3);
        const int by = lin / gridDim.x;
        m0 = by << 8; n0 = (lin - by * gridDim.x) << 8;
    } else {
        z = blockIdx.z; m0 = blockIdx.y << 8; n0 = blockIdx.x << 8;
    }

    const int h  = z / bg;
    const int bi = z - h * bg;
    A  += h * Ah + (long)bi * Ab;
    Bt += h * Bh + (long)bi * Bb;

    __shared__ __align__(16) unsigned short As[4][8192];  // [buf][256 rows x 32 k]
    __shared__ __align__(16) unsigned short Bs[4][8192];
    __shared__ float Ls[256];  // PV: summed softmax denominators

    if (SM == 4) {
        if (tid < 256) {
            const float* Lz = L + ((long)z << 10) + m0 + tid;
            const long sls = (long)gridDim.z << 10;
            float s = 0.f;
#pragma unroll
            for (int sl = 0; sl < 16; sl++) s += Lz[sl * sls];
            Ls[tid] = s;
        }
    }

    // ---- staging: linear LDS dest, inverse-swizzled global source ----
    // Per gload instr: 8 waves x 1 KB = 8 KB = 128 rows x 32 k. Wave's 16-row
    // stripe: row = wave*16 + (lane>>2), src chunk = (lane&3)^((lane>>3)&3).
    const int srow = lane >> 2;
    const int scol = ((lane & 3) ^ ((lane >> 3) & 3)) << 3;
    const unsigned short* Ag = A + (long)(m0 + wave * 16 + srow) * lda + scol;
    const unsigned short* Bg = Bt + (long)(n0 + wave * 16 + srow) * ldb + scol;

#define STA(buf, hh, kt) __builtin_amdgcn_global_load_lds( \
        (gbl_void_t*)(Ag + (long)(hh) * 128 * lda + (kt)), \
        (lds_void_t*)&As[buf][((hh) << 12) + (wave << 9)], 16, 0, 0)
#define STB(buf, hh, kt) __builtin_amdgcn_global_load_lds( \
        (gbl_void_t*)(Bg + (long)(hh) * 128 * ldb + (kt)), \
        (lds_void_t*)&Bs[buf][((hh) << 12) + (wave << 9)], 16, 0, 0)

    // ---- fragment reads (swizzled addr, verified pair with staging) ----
    const int kof = (quad ^ ((l16 >> 1) & 3)) << 3;
    const int raA = ((wm * 128 + l16) << 5) + kof;
    const int raB = ((wn * 64 + l16) << 5) + kof;

    bf16x8 ar[8];
    bf16x8 br[4];
    f32x4 acc[8][4];
#pragma unroll
    for (int i2 = 0; i2 < 8; i2++)
#pragma unroll
        for (int j2 = 0; j2 < 4; j2++) acc[i2][j2] = (f32x4){0.f, 0.f, 0.f, 0.f};

#define LDA8(buf) do { _Pragma("unroll") for (int u = 0; u < 8; u++) \
    ar[u] = *(const bf16x8*)&As[buf][raA + u * 512]; } while (0)
#define LDB4(buf) do { _Pragma("unroll") for (int v = 0; v < 4; v++) \
    br[v] = *(const bf16x8*)&Bs[buf][raB + v * 512]; } while (0)
// SM==1 unswapped (store col=l16); else swapped (row=l16, regs = 4 cols)
#define MFALL() do { _Pragma("unroll") for (int u = 0; u < 8; u++) \
    _Pragma("unroll") for (int v = 0; v < 4; v++) { \
        if (SM == 1) acc[u][v] = __builtin_amdgcn_mfma_f32_16x16x32_bf16( \
            ar[u], br[v], acc[u][v], 0, 0, 0); \
        else acc[u][v] = __builtin_amdgcn_mfma_f32_16x16x32_bf16( \
            br[v], ar[u], acc[u][v], 0, 0, 0); \
    } } while (0)

    const int NT = K >> 5;   // K-tiles of 32

    // prologue: stage tiles 0,1,2 (12 gloads); VMW(8) -> tile 0 landed
    STA(0, 0, 0);  STA(0, 1, 0);  STB(0, 0, 0);  STB(0, 1, 0);
    STA(1, 0, 32); STA(1, 1, 32); STB(1, 0, 32); STB(1, 1, 32);
    STA(2, 0, 64); STA(2, 1, 64); STB(2, 0, 64); STB(2, 1, 64);
    VMW(8);
    __builtin_amdgcn_s_barrier();

    for (int t = 0; t < NT; t++) {
        const int bcur = t & 3;
        const int bstg = (t + 3) & 3;
        const int kstg = (t + 3) << 5;
        LDA8(bcur); LDB4(bcur);
        if (t + 3 < NT) {
            STA(bstg, 0, kstg); STA(bstg, 1, kstg);
            STB(bstg, 0, kstg); STB(bstg, 1, kstg);
            VMW(8);                       // oldest 4 = tile t+1 landed
        } else if (t == NT - 3) VMW(4);
        else if (t == NT - 2) VMW(0);
        BAR1(); MFALL(); BAR2();
    }

    // ---- epilogue (all staging DMA drained by the tail ladder) ----
    const long coff = h * Ch + (long)bi * Cb;
    if (SM == 0) {
        unsigned short* Cp = (unsigned short*)C + coff;
#pragma unroll
        for (int mi = 0; mi < 8; mi++) {
            const long rb = (long)(m0 + wm * 128 + mi * 16 + l16) * ldc;
#pragma unroll
            for (int ni = 0; ni < 4; ni++) {
                const int col = n0 + wn * 64 + ni * 16 + (quad << 2);
                us4 val = { f2bf(acc[mi][ni][0]), f2bf(acc[mi][ni][1]),
                            f2bf(acc[mi][ni][2]), f2bf(acc[mi][ni][3]) };
                *(us4*)&Cp[rb + col] = val;
            }
        }
    } else if (SM == 2) {
        float* Cp = (float*)C + coff;
#pragma unroll
        for (int mi = 0; mi < 8; mi++) {
            const long rb = (long)(m0 + wm * 128 + mi * 16 + l16) * ldc;
#pragma unroll
            for (int ni = 0; ni < 4; ni++) {
                const int col = n0 + wn * 64 + ni * 16 + (quad << 2);
                float4 v4 = { acc[mi][ni][0], acc[mi][ni][1],
                              acc[mi][ni][2], acc[mi][ni][3] };
                *(float4*)&Cp[rb + col] = v4;
            }
        }
    } else if (SM == 1) {  // VhT store, unswapped layout, us4 along s
        unsigned short* Cp = (unsigned short*)C;
#pragma unroll
        for (int mi = 0; mi < 8; mi++) {
#pragma unroll
            for (int ni = 0; ni < 4; ni++) {
                const int col = n0 + wn * 64 + ni * 16 + l16;
                const int h2 = col >> 9, d = col & 511;
                const int rowb = m0 + wm * 128 + mi * 16 + (quad << 2);
                const int bi2 = rowb >> 10, s = rowb & 1023;
                us4 val = { f2bf(acc[mi][ni][0]), f2bf(acc[mi][ni][1]),
                            f2bf(acc[mi][ni][2]), f2bf(acc[mi][ni][3]) };
                *(us4*)&Cp[(((long)(h2 * bg + bi2) * 512 + d) << 10) + s] = val;
            }
        }
    } else if (SM == 3) {
        // scores epilogue (swapped: row=l16, regs = 4 cols). Mask applied only
        // when the per-(row, 256-col-block) flag is set.
        unsigned short* Cp = (unsigned short*)C + coff;
        const unsigned char* mb = mask + ((long)(b0 + bi) << 20);
        const unsigned char* mfb = mflag + ((long)(b0 + bi) << 12);
        const int slot = (n0 >> 8) * 4 + wn;       // 4 n-blocks x 4 wn
        float* Lz = L + ((long)(slot * gridDim.z + z) << 10);
#pragma unroll
        for (int mi = 0; mi < 8; mi++) {
            const int row = m0 + wm * 128 + mi * 16 + l16;
            const long rb = (long)row * ldc;
            const unsigned char fl = mfb[(row << 2) + (n0 >> 8)];
            float rs = 0.f;
#pragma unroll
            for (int ni = 0; ni < 4; ni++) {
                const int col = n0 + wn * 64 + ni * 16 + (quad << 2);
                float p0 = __expf(acc[mi][ni][0] * inv_temp);
                float p1 = __expf(acc[mi][ni][1] * inv_temp);
                float p2 = __expf(acc[mi][ni][2] * inv_temp);
                float p3 = __expf(acc[mi][ni][3] * inv_temp);
                if (fl) {
                    const uchar4 mv = *(const uchar4*)&mb[((long)row << 10) + col];
                    if (mv.x) p0 = 0.f;
                    if (mv.y) p1 = 0.f;
                    if (mv.z) p2 = 0.f;
                    if (mv.w) p3 = 0.f;
                }
                us4 val = { f2bf(p0), f2bf(p1), f2bf(p2), f2bf(p3) };
                *(us4*)&Cp[rb + col] = val;
                rs += p0 + p1 + p2 + p3;
            }
            rs += __shfl_xor(rs, 16);
            rs += __shfl_xor(rs, 32);
            if (quad == 0) Lz[row] = rs;
        }
    } else {
        // PV epilogue: scale by 1/Ls (LDS), us4 along 4 consecutive cols.
        unsigned short* Cp = (unsigned short*)C + coff;
#pragma unroll
        for (int mi = 0; mi < 8; mi++) {
            const int ro = wm * 128 + mi * 16 + l16;
            const float inv = 1.0f / Ls[ro];
            const long rb = (long)(m0 + ro) * ldc;
#pragma unroll
            for (int ni = 0; ni < 4; ni++) {
                const int col = n0 + wn * 64 + ni * 16 + (quad << 2);
                us4 val = { f2bf(acc[mi][ni][0] * inv), f2bf(acc[mi][ni][1] * inv),
                            f2bf(acc[mi][ni][2] * inv), f2bf(acc[mi][ni][3] * inv) };
                *(us4*)&Cp[rb + col] = val;
            }
        }
    }
#undef STA
#undef STB
#undef LDA8
#undef LDB4
#undef MFALL
}
#undef VMW
#undef BAR1
#undef BAR2

// ---------------------------------------------------------------------------
// Fused: sum 8 split-K partials (f32, rows of 512) + LayerNorm -> f32 out.
// ---------------------------------------------------------------------------
__global__ __launch_bounds__(256) void ln_rows_red8(
    const float* __restrict__ Yp, long zs,
    const float* __restrict__ gamma,
    const float* __restrict__ beta,
    float* __restrict__ out)
{
    __shared__ float red[4];
    const long row = blockIdx.x;
    const float* y = Yp + (row << 9);
    const int tid = threadIdx.x;
    const int wave = tid >> 6, lane = tid & 63;

    float v0 = 0.f, v1 = 0.f;
#pragma unroll
    for (int s = 0; s < 8; s++) {
        v0 += y[s * zs + tid];
        v1 += y[s * zs + tid + 256];
    }
    float sm = v0 + v1;
#pragma unroll
    for (int i = 32; i > 0; i >>= 1) sm += __shfl_xor(sm, i);
    if (lane == 0) red[wave] = sm;
    __syncthreads();
    sm = red[0] + red[1] + red[2] + red[3];
    __syncthreads();
    const float mu = sm * (1.0f / 512.0f);

    const float d0 = v0 - mu, d1 = v1 - mu;
    float sq = d0 * d0 + d1 * d1;
#pragma unroll
    for (int i = 32; i > 0; i >>= 1) sq += __shfl_xor(sq, i);
    if (lane == 0) red[wave] = sq;
    __syncthreads();
    sq = red[0] + red[1] + red[2] + red[3];
    const float inv = rsqrtf(sq * (1.0f / 512.0f) + 1e-5f);

    out[(row << 9) + tid]       = d0 * inv * gamma[tid]       + beta[tid];
    out[(row << 9) + tid + 256] = d1 * inv * gamma[tid + 256] + beta[tid + 256];
}

// ---------------------------------------------------------------------------
extern "C" void kernel_launch(void* const* d_in, const int* in_sizes, int n_in,
                              void* d_out, int out_size, void* d_ws, size_t ws_size,
                              hipStream_t stream)
{
    const float* q_f  = (const float*)d_in[0];
    const float* k_f  = (const float*)d_in[1];
    const float* v_f  = (const float*)d_in[2];
    const float* Wq_f = (const float*)d_in[3];
    const float* Wk_f = (const float*)d_in[4];
    const float* Wv_f = (const float*)d_in[5];
    const float* Wo_f = (const float*)d_in[6];
    const float* ga_f = (const float*)d_in[7];
    const float* be_f = (const float*)d_in[8];
    const unsigned char* mask = (const unsigned char*)d_in[9];
    float* out = (float*)d_out;

    constexpr int B = 8, S = 1024, DM = 512, H = 8, DH = 512, HD = H * DH;  // HD=4096
    const float inv_temp = 0.044194173824159216f;  // 1/sqrt(512)

    size_t off = 0;
    auto alloc = [&](size_t bytes) {
        void* p = (char*)d_ws + off;
        off += (bytes + 255) & ~(size_t)255;
        return p;
    };
    unsigned short* qb  = (unsigned short*)alloc((size_t)B * S * DM * 2);
    unsigned short* kb  = (unsigned short*)alloc((size_t)B * S * DM * 2);
    unsigned short* vb  = (unsigned short*)alloc((size_t)B * S * DM * 2);
    unsigned short* WqT = (unsigned short*)alloc((size_t)HD * DM * 2);
    unsigned short* WkT = (unsigned short*)alloc((size_t)HD * DM * 2);
    unsigned short* WvT = (unsigned short*)alloc((size_t)HD * DM * 2);
    unsigned short* WoT = (unsigned short*)alloc((size_t)DH * HD * 2);
    unsigned char* mf   = (unsigned char*)alloc((size_t)B * S * 4);  // mask flags
    const size_t fixed = off;

    // AO aliases Qh (dead after scores); Ypart aliases P (dead after PV).
    const size_t perbatch = (size_t)3 * S * HD * 2   // Qh(/AO), Kh, VhT
                          + (size_t)H * S * S * 2    // P / Ypart (>= 8*S*DH*4)
                          + (size_t)16 * H * S * 4   // Lp (16 partial slots)
                          + 8 * 256;
    int bg = 8;
    while (bg > 1 && fixed + perbatch * (size_t)bg > ws_size) bg >>= 1;

    unsigned short* Qh  = (unsigned short*)alloc((size_t)bg * S * HD * 2);
    unsigned short* Kh  = (unsigned short*)alloc((size_t)bg * S * HD * 2);
    unsigned short* VhT = (unsigned short*)alloc((size_t)bg * S * HD * 2);
    unsigned short* AO  = Qh;  // alias: Qh dead once scores completes
    float* Lp = (float*)alloc((size_t)16 * H * bg * S * 4);
    void* PY = alloc((size_t)H * bg * S * S * 2);  // >= 8*bg... (split-8 Ypart)
    unsigned short* P = (unsigned short*)PY;
    float* Ypart = (float*)PY;

    // ---- canonicalization: f32 -> bf16 (+ weight transposes, mask flags) ----
    const long nqkv4 = (long)B * S * DM / 4;
    conv_f32_bf16<<<2048, 256, 0, stream>>>(q_f, qb, nqkv4);
    conv_f32_bf16<<<2048, 256, 0, stream>>>(k_f, kb, nqkv4);
    conv_f32_bf16<<<2048, 256, 0, stream>>>(v_f, vb, nqkv4);
    transpose_f32_bf16<<<dim3(HD / 64, DM / 64), 256, 0, stream>>>(Wq_f, WqT, DM, HD);
    transpose_f32_bf16<<<dim3(HD / 64, DM / 64), 256, 0, stream>>>(Wk_f, WkT, DM, HD);
    transpose_f32_bf16<<<dim3(HD / 64, DM / 64), 256, 0, stream>>>(Wv_f, WvT, DM, HD);
    transpose_f32_bf16<<<dim3(DH / 64, HD / 64), 256, 0, stream>>>(Wo_f, WoT, HD, DH);
    mask_any256<<<dim3(B * S), 256, 0, stream>>>(mask, mf);

    for (int g = 0; g < B / bg; g++) {
        const long inoff = (long)g * bg * S * DM;
        const int  Mg = bg * S;
        const int  Z  = H * bg;

        // ---- QKV projections: (Mg x 512) x (512 x 4096) ----
        gemm8w_bt<0, 1><<<dim3(HD / 256, Mg / 256, 1), 512, 0, stream>>>(
            qb + inoff, WqT, Qh, DM, DM, DM, HD, 0, 0, 0, 0, 0, 0, bg,
            nullptr, nullptr, nullptr, 0.f, 0);
        gemm8w_bt<0, 1><<<dim3(HD / 256, Mg / 256, 1), 512, 0, stream>>>(
            kb + inoff, WkT, Kh, DM, DM, DM, HD, 0, 0, 0, 0, 0, 0, bg,
            nullptr, nullptr, nullptr, 0.f, 0);
        gemm8w_bt<1, 1><<<dim3(HD / 256, Mg / 256, 1), 512, 0, stream>>>(
            vb + inoff, WvT, VhT, DM, DM, DM, HD, 0, 0, 0, 0, 0, 0, bg,
            nullptr, nullptr, nullptr, 0.f, 0);

        // ---- fused scores+exp+mask, z-chunked XCD swizzle ----
        gemm8w_bt<3, 2><<<dim3(S / 256, S / 256, Z), 512, 0, stream>>>(
            Qh, Kh, P, DH, HD, HD, S,
            (long)DH, (long)S * HD,
            (long)DH, (long)S * HD,
            (long)bg * S * S, (long)S * S,
            bg, mask, mf, Lp, inv_temp, g * bg);

        // ---- PV with 1/L normalization, z-chunked XCD swizzle ----
        gemm8w_bt<4, 2><<<dim3(DH / 256, S / 256, Z), 512, 0, stream>>>(
            P, VhT, AO, S, S, S, HD,
            (long)bg * S * S, (long)S * S,
            (long)bg * DH * S, (long)DH * S,
            (long)DH, (long)S * HD,
            bg, nullptr, nullptr, Lp, 0.f, 0);

        // ---- O-projection, split-K x8 -> Ypart (256 blocks, full CU cover) ----
        gemm8w_bt<2, 1><<<dim3(DH / 256, Mg / 256, 8), 512, 0, stream>>>(
            AO, WoT, Ypart, HD / 8, HD, HD, DH,
            512, 0, 512, 0, (long)Mg * DH, 0, 1,
            nullptr, nullptr, nullptr, 0.f, 0);

        // ---- reduce partials + LayerNorm -> f32 out ----
        ln_rows_red8<<<dim3(Mg), 256, 0, stream>>>(
            Ypart, (long)Mg * DH, ga_f, be_f, out + (long)g * bg * S * DH);
    }
}